// Round 1
// baseline (143.467 us; speedup 1.0000x reference)
//
#include <hip/hip_runtime.h>
#include <hip/hip_bf16.h>

// Problem constants (B=2, C=128, H=W=96, HEADS=8, hd=16, K=8, DIL=1, GROUPS=32)
#define BATCH 2
#define CCH   128
#define HH    96
#define WW    96
#define HWSZ  (HH*WW)        // 9216
#define HEADS 8
#define HD    16
#define KW    8
#define KK    (KW*KW)        // 64
#define GROUPS 32
#define CPG   (CCH/GROUPS)   // 4
#define GN_N  (CPG*HWSZ)     // 36864
#define EPSV  1e-6f

// ---------------------------------------------------------------------------
// Kernel 1: GroupNorm statistics. One block per (b,g); group channels are
// contiguous, so each block reduces one contiguous 36864-float range.
// ---------------------------------------------------------------------------
__global__ __launch_bounds__(256) void gn_stats_kernel(const float* __restrict__ x,
                                                       float* __restrict__ stats) {
    const int bg = blockIdx.x;                         // 0..63
    const float4* base = (const float4*)(x + (size_t)bg * GN_N);
    float s = 0.f, ss = 0.f;
    for (int i = threadIdx.x; i < GN_N / 4; i += 256) {
        float4 v = base[i];
        s  += v.x + v.y + v.z + v.w;
        ss += v.x * v.x + v.y * v.y + v.z * v.z + v.w * v.w;
    }
    #pragma unroll
    for (int off = 32; off > 0; off >>= 1) {
        s  += __shfl_down(s, off);
        ss += __shfl_down(ss, off);
    }
    __shared__ float rs[4], rss[4];
    const int wid = threadIdx.x >> 6, lane = threadIdx.x & 63;
    if (lane == 0) { rs[wid] = s; rss[wid] = ss; }
    __syncthreads();
    if (threadIdx.x == 0) {
        float S  = rs[0] + rs[1] + rs[2] + rs[3];
        float SS = rss[0] + rss[1] + rss[2] + rss[3];
        float mean = S * (1.0f / GN_N);
        float var  = SS * (1.0f / GN_N) - mean * mean;
        stats[2 * bg]     = mean;
        stats[2 * bg + 1] = rsqrtf(var + EPSV);
    }
}

// ---------------------------------------------------------------------------
// Kernel 2/4: tiled GEMM  out[b,o,p] = bias[o] + sum_c W[o,c] * X[b,c,p]
// (X optionally group-normalized on load). Tile 64(o) x 64(p), K=128 whole.
// ---------------------------------------------------------------------------
template<bool NORM, int M>
__global__ __launch_bounds__(256) void gemm_kernel(const float* __restrict__ Wm,
                                                   const float* __restrict__ X,
                                                   const float* __restrict__ bias,
                                                   const float* __restrict__ stats,
                                                   const float* __restrict__ gamma,
                                                   const float* __restrict__ beta,
                                                   float* __restrict__ out) {
    __shared__ float Wt[64][128];   // 32 KB
    __shared__ float Xt[128][64];   // 32 KB
    const int t  = threadIdx.x;
    const int pt = blockIdx.x;      // pixel tile (0..143)
    const int ot = blockIdx.y;      // output-channel tile
    const int b  = blockIdx.z;

    const float* Xb = X + (size_t)b * CCH * HWSZ + pt * 64;

    #pragma unroll
    for (int i = 0; i < 32; ++i) {
        int idx = t + i * 256;
        int o = idx >> 7, c = idx & 127;
        Wt[o][c] = Wm[(ot * 64 + o) * 128 + c];
    }
    #pragma unroll
    for (int i = 0; i < 32; ++i) {
        int idx = t + i * 256;
        int c = idx >> 6, p = idx & 63;
        float v = Xb[c * HWSZ + p];
        if (NORM) {
            int g = c >> 2;
            float mean = stats[2 * (b * GROUPS + g)];
            float rstd = stats[2 * (b * GROUPS + g) + 1];
            v = (v - mean) * rstd * gamma[c] + beta[c];
        }
        Xt[c][p] = v;
    }
    __syncthreads();

    const int tp = t & 15, to = t >> 4;
    float acc[4][4] = {};
    #pragma unroll 8
    for (int c = 0; c < 128; ++c) {
        float4 bv = *(const float4*)&Xt[c][tp * 4];
        float a0 = Wt[to * 4 + 0][c];
        float a1 = Wt[to * 4 + 1][c];
        float a2 = Wt[to * 4 + 2][c];
        float a3 = Wt[to * 4 + 3][c];
        acc[0][0] += a0 * bv.x; acc[0][1] += a0 * bv.y; acc[0][2] += a0 * bv.z; acc[0][3] += a0 * bv.w;
        acc[1][0] += a1 * bv.x; acc[1][1] += a1 * bv.y; acc[1][2] += a1 * bv.z; acc[1][3] += a1 * bv.w;
        acc[2][0] += a2 * bv.x; acc[2][1] += a2 * bv.y; acc[2][2] += a2 * bv.z; acc[2][3] += a2 * bv.w;
        acc[3][0] += a3 * bv.x; acc[3][1] += a3 * bv.y; acc[3][2] += a3 * bv.z; acc[3][3] += a3 * bv.w;
    }

    #pragma unroll
    for (int j = 0; j < 4; ++j) {
        int o = ot * 64 + to * 4 + j;
        float bb = bias[o];
        float4 r;
        r.x = acc[j][0] + bb; r.y = acc[j][1] + bb;
        r.z = acc[j][2] + bb; r.w = acc[j][3] + bb;
        *(float4*)&out[((size_t)b * M + o) * HWSZ + pt * 64 + tp * 4] = r;
    }
}

// ---------------------------------------------------------------------------
// Kernel 3: neighborhood attention. One thread per (b, head, y, x).
// Window start = clamp(y-3, 0, 88) (K=8, DIL=1). All loops fully unrolled so
// logits stay in registers.
// ---------------------------------------------------------------------------
__global__ __launch_bounds__(256) void natten_kernel(const float* __restrict__ qkv,
                                                     float* __restrict__ attn_out) {
    const int idx = blockIdx.x * 256 + threadIdx.x;    // 0..147455
    const int x = idx % WW;
    const int y = (idx / WW) % HH;
    const int h = (idx / HWSZ) % HEADS;
    const int b = idx / (HWSZ * HEADS);

    const size_t bb = (size_t)b * (3 * CCH) * HWSZ;
    const float* qp = qkv + bb + (0 * CCH + h * HD) * HWSZ + y * WW + x;
    const float* kp = qkv + bb + (1 * CCH + h * HD) * HWSZ;
    const float* vp = qkv + bb + (2 * CCH + h * HD) * HWSZ;

    int sy = y - 3; sy = sy < 0 ? 0 : (sy > HH - KW ? HH - KW : sy);
    int sx = x - 3; sx = sx < 0 ? 0 : (sx > WW - KW ? WW - KW : sx);

    float q[HD];
    #pragma unroll
    for (int c = 0; c < HD; ++c) q[c] = qp[c * HWSZ] * 0.25f;   // 1/sqrt(16)

    float lg[KK];
    #pragma unroll
    for (int ky = 0; ky < KW; ++ky) {
        const float* krow = kp + (sy + ky) * WW + sx;
        #pragma unroll
        for (int kx = 0; kx < KW; ++kx) {
            float s = 0.f;
            #pragma unroll
            for (int c = 0; c < HD; ++c) s += q[c] * krow[c * HWSZ + kx];
            lg[ky * KW + kx] = s;
        }
    }

    float m = lg[0];
    #pragma unroll
    for (int i = 1; i < KK; ++i) m = fmaxf(m, lg[i]);
    float sum = 0.f;
    #pragma unroll
    for (int i = 0; i < KK; ++i) { lg[i] = __expf(lg[i] - m); sum += lg[i]; }
    const float inv = 1.0f / sum;

    float acc[HD] = {};
    #pragma unroll
    for (int ky = 0; ky < KW; ++ky) {
        #pragma unroll
        for (int kx = 0; kx < KW; ++kx) {
            float p = lg[ky * KW + kx];
            const float* vrow = vp + (sy + ky) * WW + sx + kx;
            #pragma unroll
            for (int c = 0; c < HD; ++c) acc[c] += p * vrow[c * HWSZ];
        }
    }

    float* op = attn_out + (size_t)b * CCH * HWSZ + (h * HD) * HWSZ + y * WW + x;
    #pragma unroll
    for (int c = 0; c < HD; ++c) op[c * HWSZ] = acc[c] * inv;
}

// ---------------------------------------------------------------------------
extern "C" void kernel_launch(void* const* d_in, const int* in_sizes, int n_in,
                              void* d_out, int out_size, void* d_ws, size_t ws_size,
                              hipStream_t stream) {
    const float* x      = (const float*)d_in[0];
    const float* gamma  = (const float*)d_in[1];
    const float* beta   = (const float*)d_in[2];
    const float* qkv_w  = (const float*)d_in[3];
    const float* qkv_b  = (const float*)d_in[4];
    const float* proj_w = (const float*)d_in[5];
    const float* proj_b = (const float*)d_in[6];
    float* out = (float*)d_out;

    float* ws       = (float*)d_ws;
    float* stats    = ws;                               // 128 floats
    float* qkv      = ws + 128;                         // 2*384*9216 = 7,077,888
    float* attn_out = qkv + (size_t)BATCH * 3 * CCH * HWSZ;  // 2,359,296

    gn_stats_kernel<<<BATCH * GROUPS, 256, 0, stream>>>(x, stats);

    gemm_kernel<true, 3 * CCH><<<dim3(HWSZ / 64, (3 * CCH) / 64, BATCH), 256, 0, stream>>>(
        qkv_w, x, qkv_b, stats, gamma, beta, qkv);

    natten_kernel<<<(BATCH * HEADS * HWSZ) / 256, 256, 0, stream>>>(qkv, attn_out);

    gemm_kernel<false, CCH><<<dim3(HWSZ / 64, CCH / 64, BATCH), 256, 0, stream>>>(
        proj_w, attn_out, proj_b, nullptr, nullptr, nullptr, out);
}

// Round 2
// 119.186 us; speedup vs baseline: 1.2037x; 1.2037x over previous
//
#include <hip/hip_runtime.h>
#include <hip/hip_bf16.h>

#define BATCH 2
#define CCH   128
#define HH    96
#define WW    96
#define HWSZ  (HH*WW)        // 9216
#define HEADS 8
#define HD    16
#define KW    8
#define GROUPS 32
#define EPSV  1e-6f

// ---------------------------------------------------------------------------
// GroupNorm stats, two-stage. Stage 1: 256 blocks, each reduces 9216 floats
// (one quarter of one (b,g) group). Stage 2: one tiny block combines.
// ---------------------------------------------------------------------------
__global__ __launch_bounds__(256) void gn_stage1(const float* __restrict__ x,
                                                 float* __restrict__ partial) {
    const int bq = blockIdx.x;   // (b,g,quarter) flattened: 64 groups * 4
    const float4* base = (const float4*)(x + (size_t)bq * 9216);
    float s = 0.f, ss = 0.f;
    #pragma unroll
    for (int i = 0; i < 9; ++i) {
        float4 v = base[threadIdx.x + i * 256];
        s  += v.x + v.y + v.z + v.w;
        ss += v.x * v.x + v.y * v.y + v.z * v.z + v.w * v.w;
    }
    #pragma unroll
    for (int off = 32; off > 0; off >>= 1) {
        s  += __shfl_down(s, off);
        ss += __shfl_down(ss, off);
    }
    __shared__ float rs[4], rss[4];
    const int wid = threadIdx.x >> 6, lane = threadIdx.x & 63;
    if (lane == 0) { rs[wid] = s; rss[wid] = ss; }
    __syncthreads();
    if (threadIdx.x == 0) {
        partial[2 * bq]     = rs[0] + rs[1] + rs[2] + rs[3];
        partial[2 * bq + 1] = rss[0] + rss[1] + rss[2] + rss[3];
    }
}

__global__ void gn_stage2(const float* __restrict__ partial, float* __restrict__ stats) {
    const int bg = threadIdx.x;    // 64 = B*GROUPS
    float S = 0.f, SS = 0.f;
    #pragma unroll
    for (int q = 0; q < 4; ++q) {
        S  += partial[2 * (bg * 4 + q)];
        SS += partial[2 * (bg * 4 + q) + 1];
    }
    const float mean = S * (1.f / 36864.f);
    const float var  = SS * (1.f / 36864.f) - mean * mean;
    stats[2 * bg]     = mean;
    stats[2 * bg + 1] = rsqrtf(var + EPSV);
}

// ---------------------------------------------------------------------------
// Tiled GEMM  out[b,o,p] = bias[o] + sum_c W[o,c]*X[b,c,p], K split 2x64 so
// LDS = 33 KB -> 4 blocks/CU. Wt padded [64][65] so the 4 broadcast W reads
// hit distinct banks. PIXMAJOR epilogue transposes the 64x64 tile in LDS and
// writes q/k/v pixel-major [b][s][h][p][16].
// ---------------------------------------------------------------------------
template<bool NORM, bool PIXMAJOR, int M>
__global__ __launch_bounds__(256) void gemm_kernel(const float* __restrict__ Wm,
                                                   const float* __restrict__ X,
                                                   const float* __restrict__ bias,
                                                   const float* __restrict__ stats,
                                                   const float* __restrict__ gamma,
                                                   const float* __restrict__ beta,
                                                   float* __restrict__ out) {
    __shared__ float smem[64 * 65 + 64 * 64];     // 33 KB
    float (*Wt)[65] = (float(*)[65])smem;          // [o][c_half]
    float (*Xt)[64] = (float(*)[64])(smem + 64 * 65); // [c_half][p]

    const int t  = threadIdx.x;
    const int pt = blockIdx.x, ot = blockIdx.y, b = blockIdx.z;
    const int tp = t & 15, to = t >> 4;
    const float* Xb = X + (size_t)b * CCH * HWSZ + pt * 64;

    float acc[4][4] = {};
    for (int kb = 0; kb < 2; ++kb) {
        #pragma unroll
        for (int i = 0; i < 16; ++i) {
            int idx = t + i * 256;
            int o = idx >> 6, c = idx & 63;
            Wt[o][c] = Wm[(ot * 64 + o) * 128 + kb * 64 + c];
        }
        #pragma unroll
        for (int i = 0; i < 16; ++i) {
            int idx = t + i * 256;
            int c = idx >> 6, p = idx & 63;
            int cg_ = kb * 64 + c;
            float v = Xb[(size_t)cg_ * HWSZ + p];
            if (NORM) {
                int g = cg_ >> 2;
                float mean = stats[2 * (b * GROUPS + g)];
                float rstd = stats[2 * (b * GROUPS + g) + 1];
                v = (v - mean) * rstd * gamma[cg_] + beta[cg_];
            }
            Xt[c][p] = v;
        }
        __syncthreads();
        #pragma unroll 8
        for (int c = 0; c < 64; ++c) {
            float4 bv = *(const float4*)&Xt[c][tp * 4];
            float a0 = Wt[to * 4 + 0][c];
            float a1 = Wt[to * 4 + 1][c];
            float a2 = Wt[to * 4 + 2][c];
            float a3 = Wt[to * 4 + 3][c];
            acc[0][0] += a0 * bv.x; acc[0][1] += a0 * bv.y; acc[0][2] += a0 * bv.z; acc[0][3] += a0 * bv.w;
            acc[1][0] += a1 * bv.x; acc[1][1] += a1 * bv.y; acc[1][2] += a1 * bv.z; acc[1][3] += a1 * bv.w;
            acc[2][0] += a2 * bv.x; acc[2][1] += a2 * bv.y; acc[2][2] += a2 * bv.z; acc[2][3] += a2 * bv.w;
            acc[3][0] += a3 * bv.x; acc[3][1] += a3 * bv.y; acc[3][2] += a3 * bv.z; acc[3][3] += a3 * bv.w;
        }
        __syncthreads();
    }

    if (!PIXMAJOR) {
        #pragma unroll
        for (int j = 0; j < 4; ++j) {
            int o = ot * 64 + to * 4 + j;
            float bb = bias[o];
            float4 r;
            r.x = acc[j][0] + bb; r.y = acc[j][1] + bb;
            r.z = acc[j][2] + bb; r.w = acc[j][3] + bb;
            *(float4*)&out[((size_t)b * M + o) * HWSZ + pt * 64 + tp * 4] = r;
        }
    } else {
        // transpose tile in LDS, then write pixel-major [b][s][h][p][16]
        float (*T)[68] = (float(*)[68])smem;
        #pragma unroll
        for (int j = 0; j < 4; ++j) {
            int o = ot * 64 + to * 4 + j;
            float bb = bias[o];
            #pragma unroll
            for (int i2 = 0; i2 < 4; ++i2) T[to * 4 + j][tp * 4 + i2] = acc[j][i2] + bb;
        }
        __syncthreads();
        const int o_base = ot * 64;
        const int s  = o_base >> 7;
        const int h0 = (o_base >> 4) & 7;
        #pragma unroll
        for (int i = 0; i < 4; ++i) {
            int idx = t + i * 256;
            int p = idx & 63, hc = idx >> 6;
            int h_l = hc >> 2, cg = hc & 3;
            float4 r;
            r.x = T[h_l * 16 + cg * 4 + 0][p];
            r.y = T[h_l * 16 + cg * 4 + 1][p];
            r.z = T[h_l * 16 + cg * 4 + 2][p];
            r.w = T[h_l * 16 + cg * 4 + 3][p];
            size_t base = (((size_t)b * 3 + s) * HEADS + (h0 + h_l)) * ((size_t)HWSZ * HD);
            *(float4*)&out[base + (size_t)(pt * 64 + p) * HD + cg * 4] = r;
        }
    }
}

// ---------------------------------------------------------------------------
// NATTEN: block = 12x16 query tile of one (b,h). Stage the 19x23 k/v region
// into LDS as 4 float4-planes (dense, conflict-free b128 reads). One thread
// per query, 64 logits in registers, all loops unrolled.
// ---------------------------------------------------------------------------
#define TY 12
#define TX 16
#define RH 19
#define RW 23
#define NPIX (RH*RW)   // 437

__global__ __launch_bounds__(192) void natten_kernel(const float* __restrict__ qkv,
                                                     float* __restrict__ attn_out) {
    __shared__ float Ks[4][NPIX][4];   // 27.3 KB
    __shared__ float Vs[4][NPIX][4];   // 27.3 KB
    const int tid = threadIdx.x;
    const int x0 = blockIdx.x * TX, y0 = blockIdx.y * TY;
    const int bh = blockIdx.z;
    const int h = bh & 7, b = bh >> 3;
    const int gy0 = (y0 - 3) < 0 ? 0 : (y0 - 3);
    const int gx0 = (x0 - 3) < 0 ? 0 : (x0 - 3);

    const float* Kg = qkv + (((size_t)b * 3 + 1) * HEADS + h) * ((size_t)HWSZ * HD);
    const float* Vg = qkv + (((size_t)b * 3 + 2) * HEADS + h) * ((size_t)HWSZ * HD);

    for (int i = tid; i < NPIX * 4; i += 192) {
        int pix = i >> 2, cg = i & 3;
        int r = pix / RW, cc = pix - r * RW;
        int gy = gy0 + r, gx = gx0 + cc;
        if (gy < HH && gx < WW) {
            size_t gp = (size_t)(gy * WW + gx) * HD + cg * 4;
            *(float4*)&Ks[cg][pix][0] = *(const float4*)&Kg[gp];
            *(float4*)&Vs[cg][pix][0] = *(const float4*)&Vg[gp];
        }
    }

    const int tx = tid & 15, ty = tid >> 4;
    const int y = y0 + ty, x = x0 + tx;
    int sy = y - 3; sy = sy < 0 ? 0 : (sy > HH - KW ? HH - KW : sy);
    int sx = x - 3; sx = sx < 0 ? 0 : (sx > WW - KW ? WW - KW : sx);
    const int base0 = (sy - gy0) * RW + (sx - gx0);

    const float* Qg = qkv + (((size_t)b * 3 + 0) * HEADS + h) * ((size_t)HWSZ * HD)
                    + (size_t)(y * WW + x) * HD;
    float q[16];
    #pragma unroll
    for (int cg = 0; cg < 4; ++cg) {
        float4 qv = *(const float4*)&Qg[cg * 4];
        q[cg * 4 + 0] = qv.x * 0.25f; q[cg * 4 + 1] = qv.y * 0.25f;
        q[cg * 4 + 2] = qv.z * 0.25f; q[cg * 4 + 3] = qv.w * 0.25f;
    }
    __syncthreads();

    float lg[64];
    #pragma unroll
    for (int ky = 0; ky < 8; ++ky) {
        int rb = base0 + ky * RW;
        #pragma unroll
        for (int kx = 0; kx < 8; ++kx) {
            int pix = rb + kx;
            float s = 0.f;
            #pragma unroll
            for (int cg = 0; cg < 4; ++cg) {
                float4 kv = *(const float4*)&Ks[cg][pix][0];
                s += q[cg * 4 + 0] * kv.x + q[cg * 4 + 1] * kv.y
                   + q[cg * 4 + 2] * kv.z + q[cg * 4 + 3] * kv.w;
            }
            lg[ky * 8 + kx] = s;
        }
    }

    float m = lg[0];
    #pragma unroll
    for (int i = 1; i < 64; ++i) m = fmaxf(m, lg[i]);
    float sum = 0.f;
    #pragma unroll
    for (int i = 0; i < 64; ++i) { lg[i] = __expf(lg[i] - m); sum += lg[i]; }
    const float inv = 1.f / sum;

    float acc[16] = {};
    #pragma unroll
    for (int ky = 0; ky < 8; ++ky) {
        int rb = base0 + ky * RW;
        #pragma unroll
        for (int kx = 0; kx < 8; ++kx) {
            int pix = rb + kx;
            float p = lg[ky * 8 + kx];
            #pragma unroll
            for (int cg = 0; cg < 4; ++cg) {
                float4 vv = *(const float4*)&Vs[cg][pix][0];
                acc[cg * 4 + 0] += p * vv.x; acc[cg * 4 + 1] += p * vv.y;
                acc[cg * 4 + 2] += p * vv.z; acc[cg * 4 + 3] += p * vv.w;
            }
        }
    }

    float* op = attn_out + ((size_t)b * CCH + h * HD) * HWSZ + y * WW + x;
    #pragma unroll
    for (int c = 0; c < 16; ++c) op[c * HWSZ] = acc[c] * inv;
}

// ---------------------------------------------------------------------------
extern "C" void kernel_launch(void* const* d_in, const int* in_sizes, int n_in,
                              void* d_out, int out_size, void* d_ws, size_t ws_size,
                              hipStream_t stream) {
    const float* x      = (const float*)d_in[0];
    const float* gamma  = (const float*)d_in[1];
    const float* beta   = (const float*)d_in[2];
    const float* qkv_w  = (const float*)d_in[3];
    const float* qkv_b  = (const float*)d_in[4];
    const float* proj_w = (const float*)d_in[5];
    const float* proj_b = (const float*)d_in[6];
    float* out = (float*)d_out;

    float* ws      = (float*)d_ws;
    float* stats   = ws;                 // 128 floats
    float* partial = ws + 128;           // 512 floats
    float* qkv     = ws + 1024;          // 2*3*8*9216*16 = 7,077,888 floats (pixel-major)
    float* attn    = qkv + (size_t)BATCH * 3 * HEADS * HWSZ * HD;   // 2,359,296 floats

    gn_stage1<<<256, 256, 0, stream>>>(x, partial);
    gn_stage2<<<1, 64, 0, stream>>>(partial, stats);

    gemm_kernel<true, true, 3 * CCH><<<dim3(HWSZ / 64, 6, BATCH), 256, 0, stream>>>(
        qkv_w, x, qkv_b, stats, gamma, beta, qkv);

    natten_kernel<<<dim3(WW / TX, HH / TY, BATCH * HEADS), 192, 0, stream>>>(qkv, attn);

    gemm_kernel<false, false, CCH><<<dim3(HWSZ / 64, 2, BATCH), 256, 0, stream>>>(
        proj_w, attn, proj_b, nullptr, nullptr, nullptr, out);
}

// Round 3
// 57.968 us; speedup vs baseline: 2.4750x; 2.0561x over previous
//
#include <hip/hip_runtime.h>
#include <hip/hip_bf16.h>

typedef unsigned short u16;
typedef unsigned int   u32;
typedef __attribute__((ext_vector_type(8))) short short8;
typedef __attribute__((ext_vector_type(4))) float f32x4;

#define BATCH 2
#define CCH   128
#define HH    96
#define WW    96
#define HWSZ  9216
#define HEADS 8
#define HD    16
#define KW    8
#define GROUPS 32
#define EPSV  1e-6f
#define PLN   24              // 3*HEADS pixel-major planes per batch

static __device__ __forceinline__ u16 f2bf(float f) {
    u32 u = __builtin_bit_cast(u32, f);
    u = (u + 0x7FFFu + ((u >> 16) & 1u)) >> 16;      // RNE, finite values
    return (u16)u;
}
static __device__ __forceinline__ float bf_lo(u32 w) { return __builtin_bit_cast(float, w << 16); }
static __device__ __forceinline__ float bf_hi(u32 w) { return __builtin_bit_cast(float, w & 0xFFFF0000u); }

// ---------------------------------------------------------------------------
// GroupNorm stats (two-stage, unchanged from round 2)
// ---------------------------------------------------------------------------
__global__ __launch_bounds__(256) void gn_stage1(const float* __restrict__ x,
                                                 float* __restrict__ partial) {
    const int bq = blockIdx.x;
    const float4* base = (const float4*)(x + (size_t)bq * 9216);
    float s = 0.f, ss = 0.f;
    #pragma unroll
    for (int i = 0; i < 9; ++i) {
        float4 v = base[threadIdx.x + i * 256];
        s  += v.x + v.y + v.z + v.w;
        ss += v.x * v.x + v.y * v.y + v.z * v.z + v.w * v.w;
    }
    #pragma unroll
    for (int off = 32; off > 0; off >>= 1) {
        s  += __shfl_down(s, off);
        ss += __shfl_down(ss, off);
    }
    __shared__ float rs[4], rss[4];
    const int wid = threadIdx.x >> 6, lane = threadIdx.x & 63;
    if (lane == 0) { rs[wid] = s; rss[wid] = ss; }
    __syncthreads();
    if (threadIdx.x == 0) {
        partial[2 * bq]     = rs[0] + rs[1] + rs[2] + rs[3];
        partial[2 * bq + 1] = rss[0] + rss[1] + rss[2] + rss[3];
    }
}

__global__ void gn_stage2(const float* __restrict__ partial, float* __restrict__ stats) {
    const int bg = threadIdx.x;    // 64
    float S = 0.f, SS = 0.f;
    #pragma unroll
    for (int qq = 0; qq < 4; ++qq) {
        S  += partial[2 * (bg * 4 + qq)];
        SS += partial[2 * (bg * 4 + qq) + 1];
    }
    const float mean = S * (1.f / 36864.f);
    const float var  = SS * (1.f / 36864.f) - mean * mean;
    stats[2 * bg]     = mean;
    stats[2 * bg + 1] = rsqrtf(var + EPSV);
}

// ---------------------------------------------------------------------------
// prep_x: normalize x and pack bf16 k-packed: Xp[b][cb=16][p=9216][8]
// ---------------------------------------------------------------------------
__global__ __launch_bounds__(256) void prep_x(const float* __restrict__ x,
                                              const float* __restrict__ stats,
                                              const float* __restrict__ gamma,
                                              const float* __restrict__ beta,
                                              u16* __restrict__ Xp) {
    const int p  = blockIdx.x * 256 + threadIdx.x;
    const int cb = blockIdx.y, b = blockIdx.z;
    u16 pk[8];
    #pragma unroll
    for (int j = 0; j < 8; ++j) {
        int c = cb * 8 + j, g = c >> 2;
        float mean = stats[2 * (b * GROUPS + g)];
        float rstd = stats[2 * (b * GROUPS + g) + 1];
        float v = x[((size_t)(b * CCH + c)) * HWSZ + p];
        pk[j] = f2bf((v - mean) * rstd * gamma[c] + beta[c]);
    }
    uint4 o;
    o.x = (u32)pk[0] | ((u32)pk[1] << 16);
    o.y = (u32)pk[2] | ((u32)pk[3] << 16);
    o.z = (u32)pk[4] | ((u32)pk[5] << 16);
    o.w = (u32)pk[6] | ((u32)pk[7] << 16);
    *(uint4*)(Xp + (((size_t)(b * 16 + cb)) * HWSZ + p) * 8) = o;
}

// ---------------------------------------------------------------------------
// prep_w: pack qkv_w -> Wq[cb][384][8], proj_w -> Wp[cb][128][8] (bf16)
// ---------------------------------------------------------------------------
__global__ __launch_bounds__(256) void prep_w(const float* __restrict__ qkv_w,
                                              const float* __restrict__ proj_w,
                                              u16* __restrict__ Wq, u16* __restrict__ Wp) {
    const int t = blockIdx.x * 256 + threadIdx.x;
    if (t < 16 * 384) {
        int cb = t / 384, o = t % 384;
        u16 pk[8];
        #pragma unroll
        for (int j = 0; j < 8; ++j) pk[j] = f2bf(qkv_w[o * 128 + cb * 8 + j]);
        uint4 r;
        r.x = (u32)pk[0] | ((u32)pk[1] << 16); r.y = (u32)pk[2] | ((u32)pk[3] << 16);
        r.z = (u32)pk[4] | ((u32)pk[5] << 16); r.w = (u32)pk[6] | ((u32)pk[7] << 16);
        *(uint4*)(Wq + (size_t)t * 8) = r;
    } else if (t < 16 * 384 + 16 * 128) {
        int i = t - 16 * 384;
        int cb = i / 128, o = i % 128;
        u16 pk[8];
        #pragma unroll
        for (int j = 0; j < 8; ++j) pk[j] = f2bf(proj_w[o * 128 + cb * 8 + j]);
        uint4 r;
        r.x = (u32)pk[0] | ((u32)pk[1] << 16); r.y = (u32)pk[2] | ((u32)pk[3] << 16);
        r.z = (u32)pk[4] | ((u32)pk[5] << 16); r.w = (u32)pk[6] | ((u32)pk[7] << 16);
        *(uint4*)(Wp + (size_t)i * 8) = r;
    }
}

// ---------------------------------------------------------------------------
// MFMA GEMM, no LDS: C[o][p] = sum_c W[o][c]*X[c][p] + bias[o].
// A-frag (row o): lane reads 8 contiguous k from Wpk[cb][o][8], cb=ks*4+(l>>4).
// B-frag (col p): lane reads 8 contiguous k from Xpk[cb][p][8].
// D: row o=(l>>4)*4+r, col p=(l&15)  [m89 verified].
// Block = 4 waves = 128o x 128p tile; wave = 64o x 64p = 4x4 frags.
// QKV_OUT: write bf16 pixel-major qkv[plane=b*24+(o>>4)][p][o&15].
// else: write fp32 channel-major out[b][o][p].
// ---------------------------------------------------------------------------
template<int MTOT, bool QKV_OUT>
__global__ __launch_bounds__(256) void mfma_gemm(const u16* __restrict__ Wpk,
                                                 const u16* __restrict__ Xpk,
                                                 const float* __restrict__ bias,
                                                 u16* __restrict__ out_bf,
                                                 float* __restrict__ out_f32) {
    const int l = threadIdx.x & 63, w = threadIdx.x >> 6;
    const int pt = blockIdx.x, ot = blockIdx.y, b = blockIdx.z;
    const int OB = ot * 128 + (w & 1) * 64;
    const int PB = pt * 128 + (w >> 1) * 64;
    const int q = l >> 4, lo = l & 15;
    const u16* Xb = Xpk + (size_t)b * 16 * HWSZ * 8;

    float bv[4][4];
    #pragma unroll
    for (int of = 0; of < 4; ++of)
        #pragma unroll
        for (int r = 0; r < 4; ++r) bv[of][r] = bias[OB + of * 16 + q * 4 + r];

    f32x4 acc[4][4] = {};   // [of][pf]
    #pragma unroll
    for (int ks = 0; ks < 4; ++ks) {
        const int cb = ks * 4 + q;
        short8 a[4];
        #pragma unroll
        for (int of = 0; of < 4; ++of)
            a[of] = *(const short8*)(Wpk + ((size_t)cb * MTOT + OB + of * 16 + lo) * 8);
        #pragma unroll
        for (int pf = 0; pf < 4; ++pf) {
            short8 bb = *(const short8*)(Xb + ((size_t)cb * HWSZ + PB + pf * 16 + lo) * 8);
            #pragma unroll
            for (int of = 0; of < 4; ++of)
                acc[of][pf] = __builtin_amdgcn_mfma_f32_16x16x32_bf16(a[of], bb, acc[of][pf], 0, 0, 0);
        }
    }

    if (QKV_OUT) {
        #pragma unroll
        for (int of = 0; of < 4; ++of) {
            const int plane = b * PLN + (OB >> 4) + of;
            #pragma unroll
            for (int pf = 0; pf < 4; ++pf) {
                const int p = PB + pf * 16 + lo;
                u16 h0 = f2bf(acc[of][pf][0] + bv[of][0]);
                u16 h1 = f2bf(acc[of][pf][1] + bv[of][1]);
                u16 h2 = f2bf(acc[of][pf][2] + bv[of][2]);
                u16 h3 = f2bf(acc[of][pf][3] + bv[of][3]);
                uint2 pkt;
                pkt.x = (u32)h0 | ((u32)h1 << 16);
                pkt.y = (u32)h2 | ((u32)h3 << 16);
                *(uint2*)(out_bf + ((size_t)plane * HWSZ + p) * 16 + q * 4) = pkt;
            }
        }
    } else {
        #pragma unroll
        for (int of = 0; of < 4; ++of) {
            #pragma unroll
            for (int pf = 0; pf < 4; ++pf) {
                const int p = PB + pf * 16 + lo;
                #pragma unroll
                for (int r = 0; r < 4; ++r) {
                    const int o = OB + of * 16 + q * 4 + r;
                    out_f32[((size_t)(b * MTOT + o)) * HWSZ + p] = acc[of][pf][r] + bv[of][r];
                }
            }
        }
    }
}

// ---------------------------------------------------------------------------
// NATTEN (round-2 verified structure): block = 12x16 query tile of one (b,h),
// stage 19x23 k/v region to fp32 LDS (convert bf16 once at staging).
// Output: proj B-operand k-packed bf16 attn[b][cb=16][p][8].
// ---------------------------------------------------------------------------
#define TY 12
#define TX 16
#define RH 19
#define RW 23
#define NPIX (RH*RW)   // 437

__global__ __launch_bounds__(192) void natten_kernel(const u16* __restrict__ qkv,
                                                     u16* __restrict__ attn_out) {
    __shared__ float Ks[4][NPIX][4];
    __shared__ float Vs[4][NPIX][4];
    const int tid = threadIdx.x;
    const int x0 = blockIdx.x * TX, y0 = blockIdx.y * TY;
    const int bh = blockIdx.z;
    const int h = bh & 7, b = bh >> 3;
    const int gy0 = (y0 - 3) < 0 ? 0 : (y0 - 3);
    const int gx0 = (x0 - 3) < 0 ? 0 : (x0 - 3);

    const u16* Kg = qkv + (size_t)(b * PLN + HEADS + h) * HWSZ * HD;
    const u16* Vg = qkv + (size_t)(b * PLN + 2 * HEADS + h) * HWSZ * HD;

    for (int i = tid; i < NPIX * 2; i += 192) {
        int pix = i >> 1, half = i & 1;
        int r = pix / RW, cc = pix - r * RW;
        int gy = gy0 + r, gx = gx0 + cc;
        if (gy < HH && gx < WW) {
            size_t gp = (size_t)(gy * WW + gx) * HD + half * 8;
            uint4 kv = *(const uint4*)(Kg + gp);
            uint4 vv = *(const uint4*)(Vg + gp);
            int cg = half * 2;
            float4 ka = make_float4(bf_lo(kv.x), bf_hi(kv.x), bf_lo(kv.y), bf_hi(kv.y));
            float4 kb = make_float4(bf_lo(kv.z), bf_hi(kv.z), bf_lo(kv.w), bf_hi(kv.w));
            float4 va = make_float4(bf_lo(vv.x), bf_hi(vv.x), bf_lo(vv.y), bf_hi(vv.y));
            float4 vb = make_float4(bf_lo(vv.z), bf_hi(vv.z), bf_lo(vv.w), bf_hi(vv.w));
            *(float4*)&Ks[cg][pix][0]     = ka;
            *(float4*)&Ks[cg + 1][pix][0] = kb;
            *(float4*)&Vs[cg][pix][0]     = va;
            *(float4*)&Vs[cg + 1][pix][0] = vb;
        }
    }

    const int tx = tid & 15, ty = tid >> 4;
    const int y = y0 + ty, x = x0 + tx;
    int sy = y - 3; sy = sy < 0 ? 0 : (sy > HH - KW ? HH - KW : sy);
    int sx = x - 3; sx = sx < 0 ? 0 : (sx > WW - KW ? WW - KW : sx);
    const int base0 = (sy - gy0) * RW + (sx - gx0);

    const u16* Qg = qkv + (size_t)(b * PLN + h) * HWSZ * HD + (size_t)(y * WW + x) * HD;
    uint4 q0 = *(const uint4*)Qg;
    uint4 q1 = *(const uint4*)(Qg + 8);
    float qv[16];
    qv[0]=bf_lo(q0.x)*0.25f; qv[1]=bf_hi(q0.x)*0.25f; qv[2]=bf_lo(q0.y)*0.25f; qv[3]=bf_hi(q0.y)*0.25f;
    qv[4]=bf_lo(q0.z)*0.25f; qv[5]=bf_hi(q0.z)*0.25f; qv[6]=bf_lo(q0.w)*0.25f; qv[7]=bf_hi(q0.w)*0.25f;
    qv[8]=bf_lo(q1.x)*0.25f; qv[9]=bf_hi(q1.x)*0.25f; qv[10]=bf_lo(q1.y)*0.25f; qv[11]=bf_hi(q1.y)*0.25f;
    qv[12]=bf_lo(q1.z)*0.25f; qv[13]=bf_hi(q1.z)*0.25f; qv[14]=bf_lo(q1.w)*0.25f; qv[15]=bf_hi(q1.w)*0.25f;
    __syncthreads();

    float lg[64];
    #pragma unroll
    for (int ky = 0; ky < 8; ++ky) {
        int rb = base0 + ky * RW;
        #pragma unroll
        for (int kx = 0; kx < 8; ++kx) {
            int pix = rb + kx;
            float s = 0.f;
            #pragma unroll
            for (int cg = 0; cg < 4; ++cg) {
                float4 kv = *(const float4*)&Ks[cg][pix][0];
                s += qv[cg * 4 + 0] * kv.x + qv[cg * 4 + 1] * kv.y
                   + qv[cg * 4 + 2] * kv.z + qv[cg * 4 + 3] * kv.w;
            }
            lg[ky * 8 + kx] = s;
        }
    }

    float m = lg[0];
    #pragma unroll
    for (int i = 1; i < 64; ++i) m = fmaxf(m, lg[i]);
    float sum = 0.f;
    #pragma unroll
    for (int i = 0; i < 64; ++i) { lg[i] = __expf(lg[i] - m); sum += lg[i]; }
    const float inv = 1.f / sum;

    float acc[16] = {};
    #pragma unroll
    for (int ky = 0; ky < 8; ++ky) {
        int rb = base0 + ky * RW;
        #pragma unroll
        for (int kx = 0; kx < 8; ++kx) {
            int pix = rb + kx;
            float p = lg[ky * 8 + kx];
            #pragma unroll
            for (int cg = 0; cg < 4; ++cg) {
                float4 vv = *(const float4*)&Vs[cg][pix][0];
                acc[cg * 4 + 0] += p * vv.x; acc[cg * 4 + 1] += p * vv.y;
                acc[cg * 4 + 2] += p * vv.z; acc[cg * 4 + 3] += p * vv.w;
            }
        }
    }

    // write k-packed bf16 for proj B-side: attn[b][cb][p][8], cb = h*2+{0,1}
    const int p = y * WW + x;
    #pragma unroll
    for (int jj = 0; jj < 2; ++jj) {
        u16 pk[8];
        #pragma unroll
        for (int j = 0; j < 8; ++j) pk[j] = f2bf(acc[jj * 8 + j] * inv);
        uint4 o;
        o.x = (u32)pk[0] | ((u32)pk[1] << 16);
        o.y = (u32)pk[2] | ((u32)pk[3] << 16);
        o.z = (u32)pk[4] | ((u32)pk[5] << 16);
        o.w = (u32)pk[6] | ((u32)pk[7] << 16);
        *(uint4*)(attn_out + (((size_t)(b * 16 + h * 2 + jj)) * HWSZ + p) * 8) = o;
    }
}

// ---------------------------------------------------------------------------
extern "C" void kernel_launch(void* const* d_in, const int* in_sizes, int n_in,
                              void* d_out, int out_size, void* d_ws, size_t ws_size,
                              hipStream_t stream) {
    const float* x      = (const float*)d_in[0];
    const float* gamma  = (const float*)d_in[1];
    const float* beta   = (const float*)d_in[2];
    const float* qkv_w  = (const float*)d_in[3];
    const float* qkv_b  = (const float*)d_in[4];
    const float* proj_w = (const float*)d_in[5];
    const float* proj_b = (const float*)d_in[6];
    float* out = (float*)d_out;

    char* wsb = (char*)d_ws;
    float* partial = (float*)wsb;                    // 512 f32
    float* stats   = (float*)(wsb + 2048);           // 128 f32
    u16* Xp    = (u16*)(wsb + 4096);                               // 2,359,296 u16
    u16* Wq    = Xp + (size_t)BATCH * 16 * HWSZ * 8;               // 49,152 u16
    u16* Wp    = Wq + 16 * 384 * 8;                                // 16,384 u16
    u16* qkvp  = Wp + 16 * 128 * 8;                                // 7,077,888 u16
    u16* attnp = qkvp + (size_t)BATCH * PLN * HWSZ * HD;           // 2,359,296 u16

    gn_stage1<<<256, 256, 0, stream>>>(x, partial);
    gn_stage2<<<1, 64, 0, stream>>>(partial, stats);
    prep_x<<<dim3(HWSZ / 256, 16, BATCH), 256, 0, stream>>>(x, stats, gamma, beta, Xp);
    prep_w<<<32, 256, 0, stream>>>(qkv_w, proj_w, Wq, Wp);

    mfma_gemm<384, true><<<dim3(HWSZ / 128, 3, BATCH), 256, 0, stream>>>(
        Wq, Xp, qkv_b, qkvp, nullptr);

    natten_kernel<<<dim3(WW / TX, HH / TY, BATCH * HEADS), 192, 0, stream>>>(qkvp, attnp);

    mfma_gemm<128, false><<<dim3(HWSZ / 128, 1, BATCH), 256, 0, stream>>>(
        Wp, attnp, proj_b, nullptr, out);
}

// Round 5
// 47.877 us; speedup vs baseline: 2.9966x; 1.2108x over previous
//
#include <hip/hip_runtime.h>
#include <hip/hip_bf16.h>

typedef unsigned short u16;
typedef unsigned int   u32;
typedef __attribute__((ext_vector_type(8))) short short8;
typedef __attribute__((ext_vector_type(4))) float f32x4;

#define BATCH 2
#define CCH   128
#define HH    96
#define WW    96
#define HWSZ  9216
#define HEADS 8
#define HD    16
#define GROUPS 32
#define EPSV  1e-6f
#define PLN   24

static __device__ __forceinline__ u16 f2bf(float f) {
    u32 u = __builtin_bit_cast(u32, f);
    u = (u + 0x7FFFu + ((u >> 16) & 1u)) >> 16;
    return (u16)u;
}
static __device__ __forceinline__ short8 mk8(u32 a, u32 b, u32 c, u32 d) {
    union { short8 v; u32 w[4]; } u; u.w[0]=a; u.w[1]=b; u.w[2]=c; u.w[3]=d; return u.v;
}

// ---------------------------------------------------------------------------
// GroupNorm stats (two-stage) — round-3 proven.
// ---------------------------------------------------------------------------
__global__ __launch_bounds__(256) void gn_stage1(const float* __restrict__ x,
                                                 float* __restrict__ partial) {
    const int bq = blockIdx.x;
    const float4* base = (const float4*)(x + (size_t)bq * 9216);
    float s = 0.f, ss = 0.f;
    #pragma unroll
    for (int i = 0; i < 9; ++i) {
        float4 v = base[threadIdx.x + i * 256];
        s  += v.x + v.y + v.z + v.w;
        ss += v.x * v.x + v.y * v.y + v.z * v.z + v.w * v.w;
    }
    #pragma unroll
    for (int off = 32; off > 0; off >>= 1) {
        s  += __shfl_down(s, off);
        ss += __shfl_down(ss, off);
    }
    __shared__ float rs[4], rss[4];
    const int wid = threadIdx.x >> 6, lane = threadIdx.x & 63;
    if (lane == 0) { rs[wid] = s; rss[wid] = ss; }
    __syncthreads();
    if (threadIdx.x == 0) {
        partial[2 * bq]     = rs[0] + rs[1] + rs[2] + rs[3];
        partial[2 * bq + 1] = rss[0] + rss[1] + rss[2] + rss[3];
    }
}

__global__ void gn_stage2(const float* __restrict__ partial, float* __restrict__ stats) {
    const int bg = threadIdx.x;    // 64
    float S = 0.f, SS = 0.f;
    #pragma unroll
    for (int qq = 0; qq < 4; ++qq) {
        S  += partial[2 * (bg * 4 + qq)];
        SS += partial[2 * (bg * 4 + qq) + 1];
    }
    const float mean = S * (1.f / 36864.f);
    const float var  = SS * (1.f / 36864.f) - mean * mean;
    stats[2 * bg]     = mean;
    stats[2 * bg + 1] = rsqrtf(var + EPSV);
}

// ---------------------------------------------------------------------------
// prep_x — round-3 proven.
// ---------------------------------------------------------------------------
__global__ __launch_bounds__(256) void prep_x(const float* __restrict__ x,
                                              const float* __restrict__ stats,
                                              const float* __restrict__ gamma,
                                              const float* __restrict__ beta,
                                              u16* __restrict__ Xp) {
    const int p  = blockIdx.x * 256 + threadIdx.x;
    const int cb = blockIdx.y, b = blockIdx.z;
    u16 pk[8];
    #pragma unroll
    for (int j = 0; j < 8; ++j) {
        int c = cb * 8 + j, g = c >> 2;
        float mean = stats[2 * (b * GROUPS + g)];
        float rstd = stats[2 * (b * GROUPS + g) + 1];
        float v = x[((size_t)(b * CCH + c)) * HWSZ + p];
        pk[j] = f2bf((v - mean) * rstd * gamma[c] + beta[c]);
    }
    uint4 o;
    o.x = (u32)pk[0] | ((u32)pk[1] << 16);
    o.y = (u32)pk[2] | ((u32)pk[3] << 16);
    o.z = (u32)pk[4] | ((u32)pk[5] << 16);
    o.w = (u32)pk[6] | ((u32)pk[7] << 16);
    *(uint4*)(Xp + (((size_t)(b * 16 + cb)) * HWSZ + p) * 8) = o;
}

// ---------------------------------------------------------------------------
// prep_w — round-3 proven.
// ---------------------------------------------------------------------------
__global__ __launch_bounds__(256) void prep_w(const float* __restrict__ qkv_w,
                                              const float* __restrict__ proj_w,
                                              u16* __restrict__ Wq, u16* __restrict__ Wp) {
    const int t = blockIdx.x * 256 + threadIdx.x;
    if (t < 16 * 384) {
        int cb = t / 384, o = t % 384;
        u16 pk[8];
        #pragma unroll
        for (int j = 0; j < 8; ++j) pk[j] = f2bf(qkv_w[o * 128 + cb * 8 + j]);
        uint4 r;
        r.x = (u32)pk[0] | ((u32)pk[1] << 16); r.y = (u32)pk[2] | ((u32)pk[3] << 16);
        r.z = (u32)pk[4] | ((u32)pk[5] << 16); r.w = (u32)pk[6] | ((u32)pk[7] << 16);
        *(uint4*)(Wq + (size_t)t * 8) = r;
    } else if (t < 16 * 384 + 16 * 128) {
        int i = t - 16 * 384;
        int cb = i / 128, o = i % 128;
        u16 pk[8];
        #pragma unroll
        for (int j = 0; j < 8; ++j) pk[j] = f2bf(proj_w[o * 128 + cb * 8 + j]);
        uint4 r;
        r.x = (u32)pk[0] | ((u32)pk[1] << 16); r.y = (u32)pk[2] | ((u32)pk[3] << 16);
        r.z = (u32)pk[4] | ((u32)pk[5] << 16); r.w = (u32)pk[6] | ((u32)pk[7] << 16);
        *(uint4*)(Wp + (size_t)i * 8) = r;
    }
}

// ---------------------------------------------------------------------------
// MFMA GEMM — round-3 proven (no scale fold).
// ---------------------------------------------------------------------------
template<int MTOT, bool QKV_OUT>
__global__ __launch_bounds__(256) void mfma_gemm(const u16* __restrict__ Wpk,
                                                 const u16* __restrict__ Xpk,
                                                 const float* __restrict__ bias,
                                                 u16* __restrict__ out_bf,
                                                 float* __restrict__ out_f32) {
    const int l = threadIdx.x & 63, w = threadIdx.x >> 6;
    const int pt = blockIdx.x, ot = blockIdx.y, b = blockIdx.z;
    const int OB = ot * 128 + (w & 1) * 64;
    const int PB = pt * 128 + (w >> 1) * 64;
    const int q = l >> 4, lo = l & 15;
    const u16* Xb = Xpk + (size_t)b * 16 * HWSZ * 8;

    float bv[4][4];
    #pragma unroll
    for (int of = 0; of < 4; ++of)
        #pragma unroll
        for (int r = 0; r < 4; ++r) bv[of][r] = bias[OB + of * 16 + q * 4 + r];

    f32x4 acc[4][4] = {};
    #pragma unroll
    for (int ks = 0; ks < 4; ++ks) {
        const int cb = ks * 4 + q;
        short8 a[4];
        #pragma unroll
        for (int of = 0; of < 4; ++of)
            a[of] = *(const short8*)(Wpk + ((size_t)cb * MTOT + OB + of * 16 + lo) * 8);
        #pragma unroll
        for (int pf = 0; pf < 4; ++pf) {
            short8 bb = *(const short8*)(Xb + ((size_t)cb * HWSZ + PB + pf * 16 + lo) * 8);
            #pragma unroll
            for (int of = 0; of < 4; ++of)
                acc[of][pf] = __builtin_amdgcn_mfma_f32_16x16x32_bf16(a[of], bb, acc[of][pf], 0, 0, 0);
        }
    }

    if (QKV_OUT) {
        #pragma unroll
        for (int of = 0; of < 4; ++of) {
            const int plane = b * PLN + (OB >> 4) + of;
            #pragma unroll
            for (int pf = 0; pf < 4; ++pf) {
                const int p = PB + pf * 16 + lo;
                u16 h0 = f2bf(acc[of][pf][0] + bv[of][0]);
                u16 h1 = f2bf(acc[of][pf][1] + bv[of][1]);
                u16 h2 = f2bf(acc[of][pf][2] + bv[of][2]);
                u16 h3 = f2bf(acc[of][pf][3] + bv[of][3]);
                uint2 pkt;
                pkt.x = (u32)h0 | ((u32)h1 << 16);
                pkt.y = (u32)h2 | ((u32)h3 << 16);
                *(uint2*)(out_bf + ((size_t)plane * HWSZ + p) * 16 + q * 4) = pkt;
            }
        }
    } else {
        #pragma unroll
        for (int of = 0; of < 4; ++of) {
            #pragma unroll
            for (int pf = 0; pf < 4; ++pf) {
                const int p = PB + pf * 16 + lo;
                #pragma unroll
                for (int r = 0; r < 4; ++r) {
                    const int o = OB + of * 16 + q * 4 + r;
                    out_f32[((size_t)(b * MTOT + o)) * HWSZ + p] = acc[of][pf][r] + bv[of][r];
                }
            }
        }
    }
}

// ---------------------------------------------------------------------------
// MFMA NATTEN v2 — NO inline asm. Block = (b,h) x 6-row y-band x 48-col half.
// K/V region 13x64 pixels staged bf16 in LDS. Wave: 3 groups of 16 queries
// (2y x 8x). QK: mfma(A=K dup, B=Q+zeros); C lane (q4,m) holds keys q4*4+r
// for query m -> feeds PV B-operand directly. PV A-operand (V^T) built from
// scalar LDS reads. Logits scaled 0.25 post-MFMA.
// ---------------------------------------------------------------------------
__global__ __launch_bounds__(384) void natten_mfma(const u16* __restrict__ qkv,
                                                   u16* __restrict__ attn_out) {
    __shared__ u16 KV[2][13 * 1024];
    const int tid = threadIdx.x;
    const int xh = blockIdx.x & 1, yb = blockIdx.x >> 1;
    const int h = blockIdx.y, b = blockIdx.z;
    const int ry0 = min(max(yb * 6 - 3, 0), 83);
    const int rx0 = xh * 32;

    for (int i = tid; i < 3328; i += 384) {
        const int half = i & 1, col = (i >> 1) & 63, rp = i >> 7;
        const int row = rp % 13, pl = rp / 13;
        const u16* gp = qkv + ((size_t)((b * 3 + 1 + pl) * 8 + h) * HWSZ
                             + (ry0 + row) * WW + rx0 + col) * 16 + half * 8;
        *(uint4*)&KV[pl][(row * 64 + col) * 16 + half * 8] = *(const uint4*)gp;
    }
    __syncthreads();

    const int l = tid & 63, wv = tid >> 6;
    const int m = l & 15, q4 = l >> 4;
    const int yq = m >> 3, xq = m & 7;

    for (int j = 0; j < 3; ++j) {
        const int g = wv * 3 + j;
        const int gy = g / 6, gx = g % 6;
        const int y0g = yb * 6 + gy * 2, x0g = xh * 48 + gx * 8;
        const int yabs = y0g + yq, xabs = x0g + xq;
        const int sy = min(max(yabs - 3, 0), 88);
        const int sx = min(max(xabs - 3, 0), 88);
        const int dy0 = min(max(y0g - 3, 0), 88) - ry0;
        const int rd0 = dy0 - (sy - ry0);
        const int cx0 = min(max(x0g - 3 - rx0, 0), 48);
        const int cd0 = cx0 + q4 * 4 - (sx - rx0);
        const int qpix = yabs * WW + xabs;

        const uint2 qw = *(const uint2*)(qkv + ((size_t)(b * PLN + h) * HWSZ + qpix) * 16 + q4 * 4);
        const short8 qb = mk8(qw.x, qw.y, 0u, 0u);

        float ev[9][4];
        float vs = 0.f;
        #pragma unroll
        for (int t = 0; t < 9; ++t) {
            const int trow = min(dy0 + t, 12);
            const uint2 kk = *(const uint2*)&KV[0][(trow * 64 + cx0 + m) * 16 + q4 * 4];
            f32x4 lg = __builtin_amdgcn_mfma_f32_16x16x32_bf16(
                mk8(kk.x, kk.y, kk.x, kk.y), qb, (f32x4){0.f, 0.f, 0.f, 0.f}, 0, 0, 0);
            const bool rv = (u32)(t + rd0) < 8u;
            #pragma unroll
            for (int r = 0; r < 4; ++r) {
                const bool ok = rv && ((u32)(cd0 + r) < 8u);
                const float e = ok ? __expf(lg[r] * 0.25f) : 0.f;
                ev[t][r] = e;
                vs += e;
            }
        }
        vs += __shfl_xor(vs, 16);
        vs += __shfl_xor(vs, 32);
        const float inv = 1.0f / vs;

        u32 pd0[9], pd1[9];
        #pragma unroll
        for (int t = 0; t < 9; ++t) {
            pd0[t] = (u32)f2bf(ev[t][0] * inv) | ((u32)f2bf(ev[t][1] * inv) << 16);
            pd1[t] = (u32)f2bf(ev[t][2] * inv) | ((u32)f2bf(ev[t][3] * inv) << 16);
        }

        f32x4 acc = {};
        #pragma unroll
        for (int t = 0; t < 9; ++t) {
            const int trow = min(dy0 + t, 12);
            const int kb = (trow * 64 + cx0 + q4 * 4) * 16 + m;
            u32 a0 = (u32)KV[1][kb]      | ((u32)KV[1][kb + 16] << 16);
            u32 a1 = (u32)KV[1][kb + 32] | ((u32)KV[1][kb + 48] << 16);
            acc = __builtin_amdgcn_mfma_f32_16x16x32_bf16(
                mk8(a0, a1, a0, a1), mk8(pd0[t], pd1[t], 0u, 0u), acc, 0, 0, 0);
        }

        uint2 od;
        od.x = (u32)f2bf(acc[0]) | ((u32)f2bf(acc[1]) << 16);
        od.y = (u32)f2bf(acc[2]) | ((u32)f2bf(acc[3]) << 16);
        *(uint2*)(attn_out + ((size_t)(b * 16 + h * 2 + (q4 >> 1)) * HWSZ + qpix) * 8
                  + (q4 & 1) * 4) = od;
    }
}

// ---------------------------------------------------------------------------
extern "C" void kernel_launch(void* const* d_in, const int* in_sizes, int n_in,
                              void* d_out, int out_size, void* d_ws, size_t ws_size,
                              hipStream_t stream) {
    const float* x      = (const float*)d_in[0];
    const float* gamma  = (const float*)d_in[1];
    const float* beta   = (const float*)d_in[2];
    const float* qkv_w  = (const float*)d_in[3];
    const float* qkv_b  = (const float*)d_in[4];
    const float* proj_w = (const float*)d_in[5];
    const float* proj_b = (const float*)d_in[6];
    float* out = (float*)d_out;

    char* wsb = (char*)d_ws;
    float* partial = (float*)wsb;                                   // 512 f32
    float* stats   = (float*)(wsb + 2048);                          // 128 f32
    u16* Xp    = (u16*)(wsb + 4096);                                // 2,359,296 u16
    u16* Wq    = Xp + (size_t)BATCH * 16 * HWSZ * 8;                // 49,152 u16
    u16* Wp    = Wq + 16 * 384 * 8;                                 // 16,384 u16
    u16* qkvp  = Wp + 16 * 128 * 8;                                 // 7,077,888 u16
    u16* attnp = qkvp + (size_t)BATCH * PLN * HWSZ * HD;            // 2,359,296 u16

    gn_stage1<<<256, 256, 0, stream>>>(x, partial);
    gn_stage2<<<1, 64, 0, stream>>>(partial, stats);
    prep_x<<<dim3(HWSZ / 256, 16, BATCH), 256, 0, stream>>>(x, stats, gamma, beta, Xp);
    prep_w<<<32, 256, 0, stream>>>(qkv_w, proj_w, Wq, Wp);

    mfma_gemm<384, true><<<dim3(HWSZ / 128, 3, BATCH), 256, 0, stream>>>(
        Wq, Xp, qkv_b, qkvp, nullptr);

    natten_mfma<<<dim3(32, HEADS, BATCH), 384, 0, stream>>>(qkvp, attnp);

    mfma_gemm<128, false><<<dim3(HWSZ / 128, 1, BATCH), 256, 0, stream>>>(
        Wp, attnp, proj_b, nullptr, out);
}

// Round 6
// 46.179 us; speedup vs baseline: 3.1067x; 1.0368x over previous
//
#include <hip/hip_runtime.h>
#include <hip/hip_bf16.h>

typedef unsigned short u16;
typedef unsigned int   u32;
typedef __attribute__((ext_vector_type(8))) short short8;
typedef __attribute__((ext_vector_type(4))) float f32x4;

#define BATCH 2
#define CCH   128
#define HH    96
#define WW    96
#define HWSZ  9216
#define HEADS 8
#define HD    16
#define GROUPS 32
#define EPSV  1e-6f

static __device__ __forceinline__ u16 f2bf(float f) {
    u32 u = __builtin_bit_cast(u32, f);
    u = (u + 0x7FFFu + ((u >> 16) & 1u)) >> 16;
    return (u16)u;
}
static __device__ __forceinline__ short8 mk8(u32 a, u32 b, u32 c, u32 d) {
    union { short8 v; u32 w[4]; } u; u.w[0]=a; u.w[1]=b; u.w[2]=c; u.w[3]=d; return u.v;
}

// ---------------------------------------------------------------------------
// Fused: GN partial stats (blocks 0..255) + weight packing (blocks 256..287).
// Partial layout identical to round-3/5: partial[2*bq] = sum, [2*bq+1] = sumsq,
// bq = (b*32+g)*4 + quarter (x is contiguous per (b,g) group).
// ---------------------------------------------------------------------------
__global__ __launch_bounds__(256) void gn_wpack(const float* __restrict__ x,
                                                float* __restrict__ partial,
                                                const float* __restrict__ qkv_w,
                                                const float* __restrict__ proj_w,
                                                u16* __restrict__ Wq, u16* __restrict__ Wp) {
    if (blockIdx.x < 256) {
        const int bq = blockIdx.x;
        const float4* base = (const float4*)(x + (size_t)bq * 9216);
        float s = 0.f, ss = 0.f;
        #pragma unroll
        for (int i = 0; i < 9; ++i) {
            float4 v = base[threadIdx.x + i * 256];
            s  += v.x + v.y + v.z + v.w;
            ss += v.x * v.x + v.y * v.y + v.z * v.z + v.w * v.w;
        }
        #pragma unroll
        for (int off = 32; off > 0; off >>= 1) {
            s  += __shfl_down(s, off);
            ss += __shfl_down(ss, off);
        }
        __shared__ float rs[4], rss[4];
        const int wid = threadIdx.x >> 6, lane = threadIdx.x & 63;
        if (lane == 0) { rs[wid] = s; rss[wid] = ss; }
        __syncthreads();
        if (threadIdx.x == 0) {
            partial[2 * bq]     = rs[0] + rs[1] + rs[2] + rs[3];
            partial[2 * bq + 1] = rss[0] + rss[1] + rss[2] + rss[3];
        }
    } else {
        const int t = (blockIdx.x - 256) * 256 + threadIdx.x;
        if (t < 16 * 384) {
            int cb = t / 384, o = t % 384;
            u16 pk[8];
            #pragma unroll
            for (int j = 0; j < 8; ++j) pk[j] = f2bf(qkv_w[o * 128 + cb * 8 + j]);
            uint4 r;
            r.x = (u32)pk[0] | ((u32)pk[1] << 16); r.y = (u32)pk[2] | ((u32)pk[3] << 16);
            r.z = (u32)pk[4] | ((u32)pk[5] << 16); r.w = (u32)pk[6] | ((u32)pk[7] << 16);
            *(uint4*)(Wq + (size_t)t * 8) = r;
        } else if (t < 16 * 384 + 16 * 128) {
            int i = t - 16 * 384;
            int cb = i / 128, o = i % 128;
            u16 pk[8];
            #pragma unroll
            for (int j = 0; j < 8; ++j) pk[j] = f2bf(proj_w[o * 128 + cb * 8 + j]);
            uint4 r;
            r.x = (u32)pk[0] | ((u32)pk[1] << 16); r.y = (u32)pk[2] | ((u32)pk[3] << 16);
            r.z = (u32)pk[4] | ((u32)pk[5] << 16); r.w = (u32)pk[6] | ((u32)pk[7] << 16);
            *(uint4*)(Wp + (size_t)i * 8) = r;
        }
    }
}

// ---------------------------------------------------------------------------
// prep_x: finalize stats from partial (per-block recompute, cheap), normalize,
// pack Xp[b][cb][p][8] bf16. Channels cb*8..+7 span groups cb*2, cb*2+1.
// ---------------------------------------------------------------------------
__global__ __launch_bounds__(256) void prep_x(const float* __restrict__ x,
                                              const float* __restrict__ partial,
                                              const float* __restrict__ gamma,
                                              const float* __restrict__ beta,
                                              u16* __restrict__ Xp) {
    const int p  = blockIdx.x * 256 + threadIdx.x;
    const int cb = blockIdx.y, b = blockIdx.z;
    const int bg0 = b * GROUPS + cb * 2;
    float S0 = 0.f, SS0 = 0.f, S1 = 0.f, SS1 = 0.f;
    #pragma unroll
    for (int q = 0; q < 4; ++q) {
        S0  += partial[2 * (bg0 * 4 + q)];        SS0 += partial[2 * (bg0 * 4 + q) + 1];
        S1  += partial[2 * ((bg0 + 1) * 4 + q)];  SS1 += partial[2 * ((bg0 + 1) * 4 + q) + 1];
    }
    const float mean0 = S0 * (1.f/36864.f), rstd0 = rsqrtf(SS0*(1.f/36864.f) - mean0*mean0 + EPSV);
    const float mean1 = S1 * (1.f/36864.f), rstd1 = rsqrtf(SS1*(1.f/36864.f) - mean1*mean1 + EPSV);
    u16 pk[8];
    #pragma unroll
    for (int j = 0; j < 8; ++j) {
        int c = cb * 8 + j;
        float mean = (j < 4) ? mean0 : mean1;
        float rstd = (j < 4) ? rstd0 : rstd1;
        float v = x[((size_t)(b * CCH + c)) * HWSZ + p];
        pk[j] = f2bf((v - mean) * rstd * gamma[c] + beta[c]);
    }
    uint4 o;
    o.x = (u32)pk[0] | ((u32)pk[1] << 16);
    o.y = (u32)pk[2] | ((u32)pk[3] << 16);
    o.z = (u32)pk[4] | ((u32)pk[5] << 16);
    o.w = (u32)pk[6] | ((u32)pk[7] << 16);
    *(uint4*)(Xp + (((size_t)(b * 16 + cb)) * HWSZ + p) * 8) = o;
}

// ---------------------------------------------------------------------------
// MFMA GEMM. QKV_OUT: q/k planes (pl<16) -> pixel-major qkvp[b*16+pl][p][16];
// V planes (pl>=16) -> channel-major vT[b][h][ch][p] (u16 stores, 32B runs).
// else: fp32 channel-major out.
// ---------------------------------------------------------------------------
template<int MTOT, bool QKV_OUT>
__global__ __launch_bounds__(256) void mfma_gemm(const u16* __restrict__ Wpk,
                                                 const u16* __restrict__ Xpk,
                                                 const float* __restrict__ bias,
                                                 u16* __restrict__ out_bf,
                                                 u16* __restrict__ vT,
                                                 float* __restrict__ out_f32) {
    const int l = threadIdx.x & 63, w = threadIdx.x >> 6;
    const int pt = blockIdx.x, ot = blockIdx.y, b = blockIdx.z;
    const int OB = ot * 128 + (w & 1) * 64;
    const int PB = pt * 128 + (w >> 1) * 64;
    const int q = l >> 4, lo = l & 15;
    const u16* Xb = Xpk + (size_t)b * 16 * HWSZ * 8;

    float bv[4][4];
    #pragma unroll
    for (int of = 0; of < 4; ++of)
        #pragma unroll
        for (int r = 0; r < 4; ++r) bv[of][r] = bias[OB + of * 16 + q * 4 + r];

    f32x4 acc[4][4] = {};
    #pragma unroll
    for (int ks = 0; ks < 4; ++ks) {
        const int cb = ks * 4 + q;
        short8 a[4];
        #pragma unroll
        for (int of = 0; of < 4; ++of)
            a[of] = *(const short8*)(Wpk + ((size_t)cb * MTOT + OB + of * 16 + lo) * 8);
        #pragma unroll
        for (int pf = 0; pf < 4; ++pf) {
            short8 bb = *(const short8*)(Xb + ((size_t)cb * HWSZ + PB + pf * 16 + lo) * 8);
            #pragma unroll
            for (int of = 0; of < 4; ++of)
                acc[of][pf] = __builtin_amdgcn_mfma_f32_16x16x32_bf16(a[of], bb, acc[of][pf], 0, 0, 0);
        }
    }

    if (QKV_OUT) {
        #pragma unroll
        for (int of = 0; of < 4; ++of) {
            const int pl = (OB >> 4) + of;
            if (pl < 16) {
                const int plane = b * 16 + pl;
                #pragma unroll
                for (int pf = 0; pf < 4; ++pf) {
                    const int p = PB + pf * 16 + lo;
                    u16 h0 = f2bf(acc[of][pf][0] + bv[of][0]);
                    u16 h1 = f2bf(acc[of][pf][1] + bv[of][1]);
                    u16 h2 = f2bf(acc[of][pf][2] + bv[of][2]);
                    u16 h3 = f2bf(acc[of][pf][3] + bv[of][3]);
                    uint2 pkt;
                    pkt.x = (u32)h0 | ((u32)h1 << 16);
                    pkt.y = (u32)h2 | ((u32)h3 << 16);
                    *(uint2*)(out_bf + ((size_t)plane * HWSZ + p) * 16 + q * 4) = pkt;
                }
            } else {
                const int h = pl - 16;
                #pragma unroll
                for (int pf = 0; pf < 4; ++pf) {
                    const int p = PB + pf * 16 + lo;
                    #pragma unroll
                    for (int r = 0; r < 4; ++r)
                        vT[(((size_t)(b * 8 + h)) * 16 + q * 4 + r) * HWSZ + p] =
                            f2bf(acc[of][pf][r] + bv[of][r]);
                }
            }
        }
    } else {
        #pragma unroll
        for (int of = 0; of < 4; ++of) {
            #pragma unroll
            for (int pf = 0; pf < 4; ++pf) {
                const int p = PB + pf * 16 + lo;
                #pragma unroll
                for (int r = 0; r < 4; ++r) {
                    const int o = OB + of * 16 + q * 4 + r;
                    out_f32[((size_t)(b * MTOT + o)) * HWSZ + p] = acc[of][pf][r] + bv[of][r];
                }
            }
        }
    }
}

// ---------------------------------------------------------------------------
// MFMA NATTEN v3. K staged pixel-major Ks[832][16]; V staged channel-major
// VsT[16][840] (pad 8 -> 2-way-max banks, aligned b64 reads). Per group:
// QK = 9 MFMA (dup-A), PV = 9 MFMA with A from one ds_read_b64 per tile.
// cx0 rounded to multiple of 4 for b64 alignment (strip has 4 spare cols).
// ---------------------------------------------------------------------------
__global__ __launch_bounds__(384) void natten_mfma(const u16* __restrict__ qkv,
                                                   const u16* __restrict__ vT,
                                                   u16* __restrict__ attn_out) {
    __shared__ u16 Ks[13 * 64 * 16];   // 26624 B
    __shared__ u16 VsT[16 * 840];      // 26880 B
    const int tid = threadIdx.x;
    const int xh = blockIdx.x & 1, yb = blockIdx.x >> 1;
    const int h = blockIdx.y, b = blockIdx.z;
    const int ry0 = min(max(yb * 6 - 3, 0), 83);
    const int rx0 = xh * 32;

    for (int i = tid; i < 3328; i += 384) {
        if (i < 1664) {
            const int px = i >> 1, half = i & 1;
            const int row = px >> 6, col = px & 63;
            const u16* gp = qkv + ((size_t)(b * 16 + 8 + h) * HWSZ
                                 + (ry0 + row) * WW + rx0 + col) * 16 + half * 8;
            *(uint4*)&Ks[px * 16 + half * 8] = *(const uint4*)gp;
        } else {
            const int j2 = i - 1664;
            const int ch = j2 / 104, r2 = j2 - ch * 104;
            const int row = r2 >> 3, c8 = r2 & 7;
            const u16* gp = vT + (((size_t)(b * 8 + h)) * 16 + ch) * HWSZ
                               + (ry0 + row) * WW + rx0 + c8 * 8;
            *(uint4*)&VsT[ch * 840 + row * 64 + c8 * 8] = *(const uint4*)gp;
        }
    }
    __syncthreads();

    const int l = tid & 63, wv = tid >> 6;
    const int m = l & 15, q4 = l >> 4;
    const int yq = m >> 3, xq = m & 7;

    for (int j = 0; j < 3; ++j) {
        const int g = wv * 3 + j;
        const int gy = g / 6, gx = g % 6;
        const int y0g = yb * 6 + gy * 2, x0g = xh * 48 + gx * 8;
        const int yabs = y0g + yq, xabs = x0g + xq;
        const int sy = min(max(yabs - 3, 0), 88);
        const int sx = min(max(xabs - 3, 0), 88);
        const int dy0 = min(max(y0g - 3, 0), 88) - ry0;
        const int rd0 = dy0 - (sy - ry0);
        const int cx0 = (min(max(x0g - 3 - rx0, 0), 48)) & ~3;
        const int cd0 = cx0 + q4 * 4 - (sx - rx0);
        const int qpix = yabs * WW + xabs;

        const uint2 qw = *(const uint2*)(qkv + ((size_t)(b * 16 + h) * HWSZ + qpix) * 16 + q4 * 4);
        const short8 qb = mk8(qw.x, qw.y, 0u, 0u);

        float ev[9][4];
        float vs = 0.f;
        #pragma unroll
        for (int t = 0; t < 9; ++t) {
            const int trow = min(dy0 + t, 12);
            const uint2 kk = *(const uint2*)&Ks[(trow * 64 + cx0 + m) * 16 + q4 * 4];
            f32x4 lg = __builtin_amdgcn_mfma_f32_16x16x32_bf16(
                mk8(kk.x, kk.y, kk.x, kk.y), qb, (f32x4){0.f, 0.f, 0.f, 0.f}, 0, 0, 0);
            const bool rv = (u32)(t + rd0) < 8u;
            #pragma unroll
            for (int r = 0; r < 4; ++r) {
                const bool ok = rv && ((u32)(cd0 + r) < 8u);
                const float e = ok ? __expf(lg[r] * 0.25f) : 0.f;
                ev[t][r] = e;
                vs += e;
            }
        }
        vs += __shfl_xor(vs, 16);
        vs += __shfl_xor(vs, 32);
        const float inv = 1.0f / vs;

        u32 pd0[9], pd1[9];
        #pragma unroll
        for (int t = 0; t < 9; ++t) {
            pd0[t] = (u32)f2bf(ev[t][0] * inv) | ((u32)f2bf(ev[t][1] * inv) << 16);
            pd1[t] = (u32)f2bf(ev[t][2] * inv) | ((u32)f2bf(ev[t][3] * inv) << 16);
        }

        f32x4 acc = {};
        #pragma unroll
        for (int t = 0; t < 9; ++t) {
            const int trow = min(dy0 + t, 12);
            const uint2 va = *(const uint2*)&VsT[m * 840 + trow * 64 + cx0 + q4 * 4];
            acc = __builtin_amdgcn_mfma_f32_16x16x32_bf16(
                mk8(va.x, va.y, va.x, va.y), mk8(pd0[t], pd1[t], 0u, 0u), acc, 0, 0, 0);
        }

        uint2 od;
        od.x = (u32)f2bf(acc[0]) | ((u32)f2bf(acc[1]) << 16);
        od.y = (u32)f2bf(acc[2]) | ((u32)f2bf(acc[3]) << 16);
        *(uint2*)(attn_out + ((size_t)(b * 16 + h * 2 + (q4 >> 1)) * HWSZ + qpix) * 8
                  + (q4 & 1) * 4) = od;
    }
}

// ---------------------------------------------------------------------------
extern "C" void kernel_launch(void* const* d_in, const int* in_sizes, int n_in,
                              void* d_out, int out_size, void* d_ws, size_t ws_size,
                              hipStream_t stream) {
    const float* x      = (const float*)d_in[0];
    const float* gamma  = (const float*)d_in[1];
    const float* beta   = (const float*)d_in[2];
    const float* qkv_w  = (const float*)d_in[3];
    const float* qkv_b  = (const float*)d_in[4];
    const float* proj_w = (const float*)d_in[5];
    const float* proj_b = (const float*)d_in[6];
    float* out = (float*)d_out;

    char* wsb = (char*)d_ws;
    float* partial = (float*)wsb;                                   // 512 f32
    u16* Xp    = (u16*)(wsb + 4096);                                // 2,359,296 u16
    u16* Wq    = Xp + (size_t)BATCH * 16 * HWSZ * 8;                // 49,152 u16
    u16* Wp    = Wq + 16 * 384 * 8;                                 // 16,384 u16
    u16* qkvp  = Wp + 16 * 128 * 8;                                 // 4,718,592 u16 (q,k planes)
    u16* vT    = qkvp + (size_t)BATCH * 16 * HWSZ * HD;             // 2,359,296 u16 (V ch-major)
    u16* attnp = vT + (size_t)BATCH * 8 * HD * HWSZ;                // 2,359,296 u16

    gn_wpack<<<288, 256, 0, stream>>>(x, partial, qkv_w, proj_w, Wq, Wp);
    prep_x<<<dim3(HWSZ / 256, 16, BATCH), 256, 0, stream>>>(x, partial, gamma, beta, Xp);

    mfma_gemm<384, true><<<dim3(HWSZ / 128, 3, BATCH), 256, 0, stream>>>(
        Wq, Xp, qkv_b, qkvp, vT, nullptr);

    natten_mfma<<<dim3(32, HEADS, BATCH), 384, 0, stream>>>(qkvp, vT, attnp);

    mfma_gemm<128, false><<<dim3(HWSZ / 128, 1, BATCH), 256, 0, stream>>>(
        Wp, attnp, proj_b, nullptr, nullptr, out);
}

// Round 7
// 44.582 us; speedup vs baseline: 3.2180x; 1.0358x over previous
//
#include <hip/hip_runtime.h>
#include <hip/hip_bf16.h>

typedef unsigned short u16;
typedef unsigned int   u32;
typedef __attribute__((ext_vector_type(8))) short short8;
typedef __attribute__((ext_vector_type(4))) float f32x4;

#define BATCH 2
#define CCH   128
#define HH    96
#define WW    96
#define HWSZ  9216
#define HEADS 8
#define HD    16
#define GROUPS 32
#define EPSV  1e-6f

static __device__ __forceinline__ u16 f2bf(float f) {
    u32 u = __builtin_bit_cast(u32, f);
    u = (u + 0x7FFFu + ((u >> 16) & 1u)) >> 16;
    return (u16)u;
}
static __device__ __forceinline__ short8 mk8(u32 a, u32 b, u32 c, u32 d) {
    union { short8 v; u32 w[4]; } u; u.w[0]=a; u.w[1]=b; u.w[2]=c; u.w[3]=d; return u.v;
}

// ---------------------------------------------------------------------------
// Fused: GN partial stats (blocks 0..255) + weight packing (blocks 256..287).
// partial[2*bq]=sum, [2*bq+1]=sumsq, bq=(b*32+g)*4+quarter.
// ---------------------------------------------------------------------------
__global__ __launch_bounds__(256) void gn_wpack(const float* __restrict__ x,
                                                float* __restrict__ partial,
                                                const float* __restrict__ qkv_w,
                                                const float* __restrict__ proj_w,
                                                u16* __restrict__ Wq, u16* __restrict__ Wp) {
    if (blockIdx.x < 256) {
        const int bq = blockIdx.x;
        const float4* base = (const float4*)(x + (size_t)bq * 9216);
        float s = 0.f, ss = 0.f;
        #pragma unroll
        for (int i = 0; i < 9; ++i) {
            float4 v = base[threadIdx.x + i * 256];
            s  += v.x + v.y + v.z + v.w;
            ss += v.x * v.x + v.y * v.y + v.z * v.z + v.w * v.w;
        }
        #pragma unroll
        for (int off = 32; off > 0; off >>= 1) {
            s  += __shfl_down(s, off);
            ss += __shfl_down(ss, off);
        }
        __shared__ float rs[4], rss[4];
        const int wid = threadIdx.x >> 6, lane = threadIdx.x & 63;
        if (lane == 0) { rs[wid] = s; rss[wid] = ss; }
        __syncthreads();
        if (threadIdx.x == 0) {
            partial[2 * bq]     = rs[0] + rs[1] + rs[2] + rs[3];
            partial[2 * bq + 1] = rss[0] + rss[1] + rss[2] + rss[3];
        }
    } else {
        const int t = (blockIdx.x - 256) * 256 + threadIdx.x;
        if (t < 16 * 384) {
            int cb = t / 384, o = t % 384;
            u16 pk[8];
            #pragma unroll
            for (int j = 0; j < 8; ++j) pk[j] = f2bf(qkv_w[o * 128 + cb * 8 + j]);
            uint4 r;
            r.x = (u32)pk[0] | ((u32)pk[1] << 16); r.y = (u32)pk[2] | ((u32)pk[3] << 16);
            r.z = (u32)pk[4] | ((u32)pk[5] << 16); r.w = (u32)pk[6] | ((u32)pk[7] << 16);
            *(uint4*)(Wq + (size_t)t * 8) = r;
        } else if (t < 16 * 384 + 16 * 128) {
            int i = t - 16 * 384;
            int cb = i / 128, o = i % 128;
            u16 pk[8];
            #pragma unroll
            for (int j = 0; j < 8; ++j) pk[j] = f2bf(proj_w[o * 128 + cb * 8 + j]);
            uint4 r;
            r.x = (u32)pk[0] | ((u32)pk[1] << 16); r.y = (u32)pk[2] | ((u32)pk[3] << 16);
            r.z = (u32)pk[4] | ((u32)pk[5] << 16); r.w = (u32)pk[6] | ((u32)pk[7] << 16);
            *(uint4*)(Wp + (size_t)i * 8) = r;
        }
    }
}

// ---------------------------------------------------------------------------
// QKV GEMM fused with GroupNorm-normalize staging. 1D grid of 432 blocks,
// XCD-chunk swizzled so the 3 ot-blocks sharing one x-tile land on one XCD.
// Stage: thread = (px, ch-half); 64 coalesced scalar x loads -> scale/shift
// -> k-packed bf16 Xt[16][128][8] (dense b128 writes). GEMM: B from LDS,
// A (Wq) from global/L2. Epilogue: q/k pixel-major, V channel-major.
// ---------------------------------------------------------------------------
__global__ __launch_bounds__(256) void qkv_fused(const float* __restrict__ x,
                                                 const float* __restrict__ partial,
                                                 const float* __restrict__ gamma,
                                                 const float* __restrict__ beta,
                                                 const u16* __restrict__ Wq,
                                                 const float* __restrict__ qkv_b,
                                                 u16* __restrict__ qkvp,
                                                 u16* __restrict__ vT) {
    __shared__ float scale[CCH], shift[CCH];
    __shared__ u16 Xt[16][128][8];    // 32 KB
    const int t = threadIdx.x;
    const int pph = blockIdx.x;                  // 0..431
    const int L = (pph & 7) * 54 + (pph >> 3);   // chunk swizzle (432 = 8*54)
    const int b = L / 216;
    const int r = L % 216;
    const int pt = r / 3, ot = r % 3;

    if (t < CCH) {
        const int c = t, g = c >> 2, bg = b * GROUPS + g;
        float S = 0.f, SS = 0.f;
        #pragma unroll
        for (int q = 0; q < 4; ++q) {
            S  += partial[2 * (bg * 4 + q)];
            SS += partial[2 * (bg * 4 + q) + 1];
        }
        const float mean = S * (1.f / 36864.f);
        const float rstd = rsqrtf(SS * (1.f / 36864.f) - mean * mean + EPSV);
        const float sc = rstd * gamma[c];
        scale[c] = sc;
        shift[c] = beta[c] - mean * sc;
    }
    __syncthreads();

    {
        const int px = t & 127, chh = t >> 7;
        const float* xb = x + (size_t)b * CCH * HWSZ + (size_t)pt * 128 + px;
        #pragma unroll
        for (int cbi = 0; cbi < 8; ++cbi) {
            const int cb = chh * 8 + cbi;
            u16 pk[8];
            #pragma unroll
            for (int j = 0; j < 8; ++j) {
                const int c = cb * 8 + j;
                pk[j] = f2bf(xb[(size_t)c * HWSZ] * scale[c] + shift[c]);
            }
            uint4 o;
            o.x = (u32)pk[0] | ((u32)pk[1] << 16);
            o.y = (u32)pk[2] | ((u32)pk[3] << 16);
            o.z = (u32)pk[4] | ((u32)pk[5] << 16);
            o.w = (u32)pk[6] | ((u32)pk[7] << 16);
            *(uint4*)&Xt[cb][px][0] = o;
        }
    }
    __syncthreads();

    const int l = t & 63, w = t >> 6;
    const int OB = ot * 128 + (w & 1) * 64;
    const int PL = (w >> 1) * 64;
    const int q = l >> 4, lo = l & 15;

    float bv[4][4];
    #pragma unroll
    for (int of = 0; of < 4; ++of)
        #pragma unroll
        for (int r2 = 0; r2 < 4; ++r2) bv[of][r2] = qkv_b[OB + of * 16 + q * 4 + r2];

    f32x4 acc[4][4] = {};
    #pragma unroll
    for (int ks = 0; ks < 4; ++ks) {
        const int cb = ks * 4 + q;
        short8 a[4];
        #pragma unroll
        for (int of = 0; of < 4; ++of)
            a[of] = *(const short8*)(Wq + ((size_t)cb * 384 + OB + of * 16 + lo) * 8);
        #pragma unroll
        for (int pf = 0; pf < 4; ++pf) {
            short8 bb = *(const short8*)&Xt[cb][PL + pf * 16 + lo][0];
            #pragma unroll
            for (int of = 0; of < 4; ++of)
                acc[of][pf] = __builtin_amdgcn_mfma_f32_16x16x32_bf16(a[of], bb, acc[of][pf], 0, 0, 0);
        }
    }

    #pragma unroll
    for (int of = 0; of < 4; ++of) {
        const int pl = (OB >> 4) + of;
        if (pl < 16) {
            const int plane = b * 16 + pl;
            #pragma unroll
            for (int pf = 0; pf < 4; ++pf) {
                const int p = pt * 128 + PL + pf * 16 + lo;
                u16 h0 = f2bf(acc[of][pf][0] + bv[of][0]);
                u16 h1 = f2bf(acc[of][pf][1] + bv[of][1]);
                u16 h2 = f2bf(acc[of][pf][2] + bv[of][2]);
                u16 h3 = f2bf(acc[of][pf][3] + bv[of][3]);
                uint2 pkt;
                pkt.x = (u32)h0 | ((u32)h1 << 16);
                pkt.y = (u32)h2 | ((u32)h3 << 16);
                *(uint2*)(qkvp + ((size_t)plane * HWSZ + p) * 16 + q * 4) = pkt;
            }
        } else {
            const int h = pl - 16;
            #pragma unroll
            for (int pf = 0; pf < 4; ++pf) {
                const int p = pt * 128 + PL + pf * 16 + lo;
                #pragma unroll
                for (int r2 = 0; r2 < 4; ++r2)
                    vT[(((size_t)(b * 8 + h)) * 16 + q * 4 + r2) * HWSZ + p] =
                        f2bf(acc[of][pf][r2] + bv[of][r2]);
            }
        }
    }
}

// ---------------------------------------------------------------------------
// Proj GEMM — round-6 proven (QKV_OUT=false path only).
// ---------------------------------------------------------------------------
template<int MTOT>
__global__ __launch_bounds__(256) void proj_gemm(const u16* __restrict__ Wpk,
                                                 const u16* __restrict__ Xpk,
                                                 const float* __restrict__ bias,
                                                 float* __restrict__ out_f32) {
    const int l = threadIdx.x & 63, w = threadIdx.x >> 6;
    const int pt = blockIdx.x, ot = blockIdx.y, b = blockIdx.z;
    const int OB = ot * 128 + (w & 1) * 64;
    const int PB = pt * 128 + (w >> 1) * 64;
    const int q = l >> 4, lo = l & 15;
    const u16* Xb = Xpk + (size_t)b * 16 * HWSZ * 8;

    float bv[4][4];
    #pragma unroll
    for (int of = 0; of < 4; ++of)
        #pragma unroll
        for (int r = 0; r < 4; ++r) bv[of][r] = bias[OB + of * 16 + q * 4 + r];

    f32x4 acc[4][4] = {};
    #pragma unroll
    for (int ks = 0; ks < 4; ++ks) {
        const int cb = ks * 4 + q;
        short8 a[4];
        #pragma unroll
        for (int of = 0; of < 4; ++of)
            a[of] = *(const short8*)(Wpk + ((size_t)cb * MTOT + OB + of * 16 + lo) * 8);
        #pragma unroll
        for (int pf = 0; pf < 4; ++pf) {
            short8 bb = *(const short8*)(Xb + ((size_t)cb * HWSZ + PB + pf * 16 + lo) * 8);
            #pragma unroll
            for (int of = 0; of < 4; ++of)
                acc[of][pf] = __builtin_amdgcn_mfma_f32_16x16x32_bf16(a[of], bb, acc[of][pf], 0, 0, 0);
        }
    }

    #pragma unroll
    for (int of = 0; of < 4; ++of) {
        #pragma unroll
        for (int pf = 0; pf < 4; ++pf) {
            const int p = PB + pf * 16 + lo;
            #pragma unroll
            for (int r = 0; r < 4; ++r) {
                const int o = OB + of * 16 + q * 4 + r;
                out_f32[((size_t)(b * MTOT + o)) * HWSZ + p] = acc[of][pf][r] + bv[of][r];
            }
        }
    }
}

// ---------------------------------------------------------------------------
// MFMA NATTEN v3 — round-6 proven, unchanged.
// ---------------------------------------------------------------------------
__global__ __launch_bounds__(384) void natten_mfma(const u16* __restrict__ qkv,
                                                   const u16* __restrict__ vT,
                                                   u16* __restrict__ attn_out) {
    __shared__ u16 Ks[13 * 64 * 16];
    __shared__ u16 VsT[16 * 840];
    const int tid = threadIdx.x;
    const int xh = blockIdx.x & 1, yb = blockIdx.x >> 1;
    const int h = blockIdx.y, b = blockIdx.z;
    const int ry0 = min(max(yb * 6 - 3, 0), 83);
    const int rx0 = xh * 32;

    for (int i = tid; i < 3328; i += 384) {
        if (i < 1664) {
            const int px = i >> 1, half = i & 1;
            const int row = px >> 6, col = px & 63;
            const u16* gp = qkv + ((size_t)(b * 16 + 8 + h) * HWSZ
                                 + (ry0 + row) * WW + rx0 + col) * 16 + half * 8;
            *(uint4*)&Ks[px * 16 + half * 8] = *(const uint4*)gp;
        } else {
            const int j2 = i - 1664;
            const int ch = j2 / 104, r2 = j2 - ch * 104;
            const int row = r2 >> 3, c8 = r2 & 7;
            const u16* gp = vT + (((size_t)(b * 8 + h)) * 16 + ch) * HWSZ
                               + (ry0 + row) * WW + rx0 + c8 * 8;
            *(uint4*)&VsT[ch * 840 + row * 64 + c8 * 8] = *(const uint4*)gp;
        }
    }
    __syncthreads();

    const int l = tid & 63, wv = tid >> 6;
    const int m = l & 15, q4 = l >> 4;
    const int yq = m >> 3, xq = m & 7;

    for (int j = 0; j < 3; ++j) {
        const int g = wv * 3 + j;
        const int gy = g / 6, gx = g % 6;
        const int y0g = yb * 6 + gy * 2, x0g = xh * 48 + gx * 8;
        const int yabs = y0g + yq, xabs = x0g + xq;
        const int sy = min(max(yabs - 3, 0), 88);
        const int sx = min(max(xabs - 3, 0), 88);
        const int dy0 = min(max(y0g - 3, 0), 88) - ry0;
        const int rd0 = dy0 - (sy - ry0);
        const int cx0 = (min(max(x0g - 3 - rx0, 0), 48)) & ~3;
        const int cd0 = cx0 + q4 * 4 - (sx - rx0);
        const int qpix = yabs * WW + xabs;

        const uint2 qw = *(const uint2*)(qkv + ((size_t)(b * 16 + h) * HWSZ + qpix) * 16 + q4 * 4);
        const short8 qb = mk8(qw.x, qw.y, 0u, 0u);

        float ev[9][4];
        float vs = 0.f;
        #pragma unroll
        for (int t = 0; t < 9; ++t) {
            const int trow = min(dy0 + t, 12);
            const uint2 kk = *(const uint2*)&Ks[(trow * 64 + cx0 + m) * 16 + q4 * 4];
            f32x4 lg = __builtin_amdgcn_mfma_f32_16x16x32_bf16(
                mk8(kk.x, kk.y, kk.x, kk.y), qb, (f32x4){0.f, 0.f, 0.f, 0.f}, 0, 0, 0);
            const bool rv = (u32)(t + rd0) < 8u;
            #pragma unroll
            for (int r = 0; r < 4; ++r) {
                const bool ok = rv && ((u32)(cd0 + r) < 8u);
                const float e = ok ? __expf(lg[r] * 0.25f) : 0.f;
                ev[t][r] = e;
                vs += e;
            }
        }
        vs += __shfl_xor(vs, 16);
        vs += __shfl_xor(vs, 32);
        const float inv = 1.0f / vs;

        u32 pd0[9], pd1[9];
        #pragma unroll
        for (int t = 0; t < 9; ++t) {
            pd0[t] = (u32)f2bf(ev[t][0] * inv) | ((u32)f2bf(ev[t][1] * inv) << 16);
            pd1[t] = (u32)f2bf(ev[t][2] * inv) | ((u32)f2bf(ev[t][3] * inv) << 16);
        }

        f32x4 acc = {};
        #pragma unroll
        for (int t = 0; t < 9; ++t) {
            const int trow = min(dy0 + t, 12);
            const uint2 va = *(const uint2*)&VsT[m * 840 + trow * 64 + cx0 + q4 * 4];
            acc = __builtin_amdgcn_mfma_f32_16x16x32_bf16(
                mk8(va.x, va.y, va.x, va.y), mk8(pd0[t], pd1[t], 0u, 0u), acc, 0, 0, 0);
        }

        uint2 od;
        od.x = (u32)f2bf(acc[0]) | ((u32)f2bf(acc[1]) << 16);
        od.y = (u32)f2bf(acc[2]) | ((u32)f2bf(acc[3]) << 16);
        *(uint2*)(attn_out + ((size_t)(b * 16 + h * 2 + (q4 >> 1)) * HWSZ + qpix) * 8
                  + (q4 & 1) * 4) = od;
    }
}

// ---------------------------------------------------------------------------
extern "C" void kernel_launch(void* const* d_in, const int* in_sizes, int n_in,
                              void* d_out, int out_size, void* d_ws, size_t ws_size,
                              hipStream_t stream) {
    const float* x      = (const float*)d_in[0];
    const float* gamma  = (const float*)d_in[1];
    const float* beta   = (const float*)d_in[2];
    const float* qkv_w  = (const float*)d_in[3];
    const float* qkv_b  = (const float*)d_in[4];
    const float* proj_w = (const float*)d_in[5];
    const float* proj_b = (const float*)d_in[6];
    float* out = (float*)d_out;

    char* wsb = (char*)d_ws;
    float* partial = (float*)wsb;                                   // 512 f32
    u16* Wq    = (u16*)(wsb + 4096);                                // 49,152 u16
    u16* Wp    = Wq + 16 * 384 * 8;                                 // 16,384 u16
    u16* qkvp  = Wp + 16 * 128 * 8;                                 // 4,718,592 u16 (q,k planes)
    u16* vT    = qkvp + (size_t)BATCH * 16 * HWSZ * HD;             // 2,359,296 u16 (V ch-major)
    u16* attnp = vT + (size_t)BATCH * 8 * HD * HWSZ;                // 2,359,296 u16

    gn_wpack<<<288, 256, 0, stream>>>(x, partial, qkv_w, proj_w, Wq, Wp);

    qkv_fused<<<432, 256, 0, stream>>>(x, partial, gamma, beta, Wq, qkv_b, qkvp, vT);

    natten_mfma<<<dim3(32, HEADS, BATCH), 384, 0, stream>>>(qkvp, vT, attnp);

    proj_gemm<128><<<dim3(HWSZ / 128, 1, BATCH), 256, 0, stream>>>(
        Wp, attnp, proj_b, out);
}

// Round 8
// 43.154 us; speedup vs baseline: 3.3245x; 1.0331x over previous
//
#include <hip/hip_runtime.h>
#include <hip/hip_bf16.h>

typedef unsigned short u16;
typedef unsigned int   u32;
typedef __attribute__((ext_vector_type(8))) short short8;
typedef __attribute__((ext_vector_type(4))) float f32x4;

#define BATCH 2
#define CCH   128
#define HH    96
#define WW    96
#define HWSZ  9216
#define HEADS 8
#define HD    16
#define GROUPS 32
#define EPSV  1e-6f

static __device__ __forceinline__ u16 f2bf(float f) {
    u32 u = __builtin_bit_cast(u32, f);
    u = (u + 0x7FFFu + ((u >> 16) & 1u)) >> 16;
    return (u16)u;
}
static __device__ __forceinline__ short8 mk8(u32 a, u32 b, u32 c, u32 d) {
    union { short8 v; u32 w[4]; } u; u.w[0]=a; u.w[1]=b; u.w[2]=c; u.w[3]=d; return u.v;
}

// ---------------------------------------------------------------------------
// Fused: GN partial stats (blocks 0..255) + weight packing (blocks 256..287).
// partial[2*bq]=sum, [2*bq+1]=sumsq, bq=(b*32+g)*4+quarter.
// ---------------------------------------------------------------------------
__global__ __launch_bounds__(256) void gn_wpack(const float* __restrict__ x,
                                                float* __restrict__ partial,
                                                const float* __restrict__ qkv_w,
                                                const float* __restrict__ proj_w,
                                                u16* __restrict__ Wq, u16* __restrict__ Wp) {
    if (blockIdx.x < 256) {
        const int bq = blockIdx.x;
        const float4* base = (const float4*)(x + (size_t)bq * 9216);
        float s = 0.f, ss = 0.f;
        #pragma unroll
        for (int i = 0; i < 9; ++i) {
            float4 v = base[threadIdx.x + i * 256];
            s  += v.x + v.y + v.z + v.w;
            ss += v.x * v.x + v.y * v.y + v.z * v.z + v.w * v.w;
        }
        #pragma unroll
        for (int off = 32; off > 0; off >>= 1) {
            s  += __shfl_down(s, off);
            ss += __shfl_down(ss, off);
        }
        __shared__ float rs[4], rss[4];
        const int wid = threadIdx.x >> 6, lane = threadIdx.x & 63;
        if (lane == 0) { rs[wid] = s; rss[wid] = ss; }
        __syncthreads();
        if (threadIdx.x == 0) {
            partial[2 * bq]     = rs[0] + rs[1] + rs[2] + rs[3];
            partial[2 * bq + 1] = rss[0] + rss[1] + rss[2] + rss[3];
        }
    } else {
        const int t = (blockIdx.x - 256) * 256 + threadIdx.x;
        if (t < 16 * 384) {
            int cb = t / 384, o = t % 384;
            u16 pk[8];
            #pragma unroll
            for (int j = 0; j < 8; ++j) pk[j] = f2bf(qkv_w[o * 128 + cb * 8 + j]);
            uint4 r;
            r.x = (u32)pk[0] | ((u32)pk[1] << 16); r.y = (u32)pk[2] | ((u32)pk[3] << 16);
            r.z = (u32)pk[4] | ((u32)pk[5] << 16); r.w = (u32)pk[6] | ((u32)pk[7] << 16);
            *(uint4*)(Wq + (size_t)t * 8) = r;
        } else if (t < 16 * 384 + 16 * 128) {
            int i = t - 16 * 384;
            int cb = i / 128, o = i % 128;
            u16 pk[8];
            #pragma unroll
            for (int j = 0; j < 8; ++j) pk[j] = f2bf(proj_w[o * 128 + cb * 8 + j]);
            uint4 r;
            r.x = (u32)pk[0] | ((u32)pk[1] << 16); r.y = (u32)pk[2] | ((u32)pk[3] << 16);
            r.z = (u32)pk[4] | ((u32)pk[5] << 16); r.w = (u32)pk[6] | ((u32)pk[7] << 16);
            *(uint4*)(Wp + (size_t)i * 8) = r;
        }
    }
}

// ---------------------------------------------------------------------------
// QKV GEMM fused with GroupNorm-normalize staging. 432 blocks, XCD-chunk
// swizzled so the 3 ot-blocks sharing one x-tile land on one XCD.
// smem union: staging tile Xt (16x128x8 u16 = 32 KB) / V-transpose T[128][136].
// Epilogue: q/k pixel-major uint2; V (ot==2) LDS-transposed -> uint4
// channel-major stores (coalesced 256 B runs).
// ---------------------------------------------------------------------------
__global__ __launch_bounds__(256) void qkv_fused(const float* __restrict__ x,
                                                 const float* __restrict__ partial,
                                                 const float* __restrict__ gamma,
                                                 const float* __restrict__ beta,
                                                 const u16* __restrict__ Wq,
                                                 const float* __restrict__ qkv_b,
                                                 u16* __restrict__ qkvp,
                                                 u16* __restrict__ vT) {
    __shared__ float scale[CCH], shift[CCH];
    __shared__ u16 smem[128 * 136];   // 34.8 KB union: Xt (32 KB) / T
    const int t = threadIdx.x;
    const int pph = blockIdx.x;                  // 0..431
    const int L = (pph & 7) * 54 + (pph >> 3);   // chunk swizzle (432 = 8*54)
    const int b = L / 216;
    const int r = L % 216;
    const int pt = r / 3, ot = r % 3;

    if (t < CCH) {
        const int c = t, g = c >> 2, bg = b * GROUPS + g;
        float S = 0.f, SS = 0.f;
        #pragma unroll
        for (int q = 0; q < 4; ++q) {
            S  += partial[2 * (bg * 4 + q)];
            SS += partial[2 * (bg * 4 + q) + 1];
        }
        const float mean = S * (1.f / 36864.f);
        const float rstd = rsqrtf(SS * (1.f / 36864.f) - mean * mean + EPSV);
        const float sc = rstd * gamma[c];
        scale[c] = sc;
        shift[c] = beta[c] - mean * sc;
    }
    __syncthreads();

    {
        const int px = t & 127, chh = t >> 7;
        const float* xb = x + (size_t)b * CCH * HWSZ + (size_t)pt * 128 + px;
        #pragma unroll
        for (int cbi = 0; cbi < 8; ++cbi) {
            const int cb = chh * 8 + cbi;
            u16 pk[8];
            #pragma unroll
            for (int j = 0; j < 8; ++j) {
                const int c = cb * 8 + j;
                pk[j] = f2bf(xb[(size_t)c * HWSZ] * scale[c] + shift[c]);
            }
            uint4 o;
            o.x = (u32)pk[0] | ((u32)pk[1] << 16);
            o.y = (u32)pk[2] | ((u32)pk[3] << 16);
            o.z = (u32)pk[4] | ((u32)pk[5] << 16);
            o.w = (u32)pk[6] | ((u32)pk[7] << 16);
            *(uint4*)&smem[((size_t)cb * 128 + px) * 8] = o;
        }
    }
    __syncthreads();

    const int l = t & 63, w = t >> 6;
    const int OB = ot * 128 + (w & 1) * 64;
    const int PL = (w >> 1) * 64;
    const int q = l >> 4, lo = l & 15;

    float bv[4][4];
    #pragma unroll
    for (int of = 0; of < 4; ++of)
        #pragma unroll
        for (int r2 = 0; r2 < 4; ++r2) bv[of][r2] = qkv_b[OB + of * 16 + q * 4 + r2];

    f32x4 acc[4][4] = {};
    #pragma unroll
    for (int ks = 0; ks < 4; ++ks) {
        const int cb = ks * 4 + q;
        short8 a[4];
        #pragma unroll
        for (int of = 0; of < 4; ++of)
            a[of] = *(const short8*)(Wq + ((size_t)cb * 384 + OB + of * 16 + lo) * 8);
        #pragma unroll
        for (int pf = 0; pf < 4; ++pf) {
            short8 bb = *(const short8*)&smem[((size_t)cb * 128 + PL + pf * 16 + lo) * 8];
            #pragma unroll
            for (int of = 0; of < 4; ++of)
                acc[of][pf] = __builtin_amdgcn_mfma_f32_16x16x32_bf16(a[of], bb, acc[of][pf], 0, 0, 0);
        }
    }

    if (ot < 2) {
        // q/k planes: pixel-major uint2 stores (contiguous 512 B per wave-inst)
        #pragma unroll
        for (int of = 0; of < 4; ++of) {
            const int plane = b * 16 + (OB >> 4) + of;
            #pragma unroll
            for (int pf = 0; pf < 4; ++pf) {
                const int p = pt * 128 + PL + pf * 16 + lo;
                u16 h0 = f2bf(acc[of][pf][0] + bv[of][0]);
                u16 h1 = f2bf(acc[of][pf][1] + bv[of][1]);
                u16 h2 = f2bf(acc[of][pf][2] + bv[of][2]);
                u16 h3 = f2bf(acc[of][pf][3] + bv[of][3]);
                uint2 pkt;
                pkt.x = (u32)h0 | ((u32)h1 << 16);
                pkt.y = (u32)h2 | ((u32)h3 << 16);
                *(uint2*)(qkvp + ((size_t)plane * HWSZ + p) * 16 + q * 4) = pkt;
            }
        }
    } else {
        // V planes: transpose tile in LDS, then coalesced uint4 ch-major stores
        __syncthreads();   // all waves done reading Xt
        #pragma unroll
        for (int of = 0; of < 4; ++of) {
            const int orow = (OB - 256) + of * 16 + q * 4;
            #pragma unroll
            for (int pf = 0; pf < 4; ++pf) {
                const int px = PL + pf * 16 + lo;
                #pragma unroll
                for (int r2 = 0; r2 < 4; ++r2)
                    smem[(orow + r2) * 136 + px] = f2bf(acc[of][pf][r2] + bv[of][r2]);
            }
        }
        __syncthreads();
        #pragma unroll
        for (int k = 0; k < 8; ++k) {
            const int idx = t + k * 256;
            const int row = idx >> 4, px8 = idx & 15;
            const int h = row >> 4, ch = row & 15;
            uint4 v = *(const uint4*)&smem[row * 136 + px8 * 8];
            *(uint4*)(vT + ((((size_t)(b * 8 + h)) * 16 + ch) * HWSZ)
                      + (size_t)pt * 128 + px8 * 8) = v;
        }
    }
}

// ---------------------------------------------------------------------------
// Proj GEMM: 288 blocks (2b x 144 px-tiles of 64) so all 256 CUs are busy.
// Tile 128o x 64px, 4 waves = 2 o-halves x 2 px-halves, 32 MFMA/wave.
// ---------------------------------------------------------------------------
__global__ __launch_bounds__(256) void proj_gemm(const u16* __restrict__ Wpk,
                                                 const u16* __restrict__ Xpk,
                                                 const float* __restrict__ bias,
                                                 float* __restrict__ out_f32) {
    const int bid = blockIdx.x;              // 0..287
    const int b = bid / 144, pt = bid % 144;
    const int l = threadIdx.x & 63, w = threadIdx.x >> 6;
    const int OB = (w & 1) * 64;
    const int PB = pt * 64 + (w >> 1) * 32;
    const int q = l >> 4, lo = l & 15;
    const u16* Xb = Xpk + (size_t)b * 16 * HWSZ * 8;

    float bv[4][4];
    #pragma unroll
    for (int of = 0; of < 4; ++of)
        #pragma unroll
        for (int r = 0; r < 4; ++r) bv[of][r] = bias[OB + of * 16 + q * 4 + r];

    f32x4 acc[4][2] = {};
    #pragma unroll
    for (int ks = 0; ks < 4; ++ks) {
        const int cb = ks * 4 + q;
        short8 a[4];
        #pragma unroll
        for (int of = 0; of < 4; ++of)
            a[of] = *(const short8*)(Wpk + ((size_t)cb * 128 + OB + of * 16 + lo) * 8);
        #pragma unroll
        for (int pf = 0; pf < 2; ++pf) {
            short8 bb = *(const short8*)(Xb + ((size_t)cb * HWSZ + PB + pf * 16 + lo) * 8);
            #pragma unroll
            for (int of = 0; of < 4; ++of)
                acc[of][pf] = __builtin_amdgcn_mfma_f32_16x16x32_bf16(a[of], bb, acc[of][pf], 0, 0, 0);
        }
    }

    #pragma unroll
    for (int of = 0; of < 4; ++of) {
        #pragma unroll
        for (int pf = 0; pf < 2; ++pf) {
            const int p = PB + pf * 16 + lo;
            #pragma unroll
            for (int r = 0; r < 4; ++r) {
                const int o = OB + of * 16 + q * 4 + r;
                out_f32[((size_t)(b * 128 + o)) * HWSZ + p] = acc[of][pf][r] + bv[of][r];
            }
        }
    }
}

// ---------------------------------------------------------------------------
// MFMA NATTEN v3 — round-6/7 proven, unchanged.
// ---------------------------------------------------------------------------
__global__ __launch_bounds__(384) void natten_mfma(const u16* __restrict__ qkv,
                                                   const u16* __restrict__ vT,
                                                   u16* __restrict__ attn_out) {
    __shared__ u16 Ks[13 * 64 * 16];
    __shared__ u16 VsT[16 * 840];
    const int tid = threadIdx.x;
    const int xh = blockIdx.x & 1, yb = blockIdx.x >> 1;
    const int h = blockIdx.y, b = blockIdx.z;
    const int ry0 = min(max(yb * 6 - 3, 0), 83);
    const int rx0 = xh * 32;

    for (int i = tid; i < 3328; i += 384) {
        if (i < 1664) {
            const int px = i >> 1, half = i & 1;
            const int row = px >> 6, col = px & 63;
            const u16* gp = qkv + ((size_t)(b * 16 + 8 + h) * HWSZ
                                 + (ry0 + row) * WW + rx0 + col) * 16 + half * 8;
            *(uint4*)&Ks[px * 16 + half * 8] = *(const uint4*)gp;
        } else {
            const int j2 = i - 1664;
            const int ch = j2 / 104, r2 = j2 - ch * 104;
            const int row = r2 >> 3, c8 = r2 & 7;
            const u16* gp = vT + (((size_t)(b * 8 + h)) * 16 + ch) * HWSZ
                               + (ry0 + row) * WW + rx0 + c8 * 8;
            *(uint4*)&VsT[ch * 840 + row * 64 + c8 * 8] = *(const uint4*)gp;
        }
    }
    __syncthreads();

    const int l = tid & 63, wv = tid >> 6;
    const int m = l & 15, q4 = l >> 4;
    const int yq = m >> 3, xq = m & 7;

    for (int j = 0; j < 3; ++j) {
        const int g = wv * 3 + j;
        const int gy = g / 6, gx = g % 6;
        const int y0g = yb * 6 + gy * 2, x0g = xh * 48 + gx * 8;
        const int yabs = y0g + yq, xabs = x0g + xq;
        const int sy = min(max(yabs - 3, 0), 88);
        const int sx = min(max(xabs - 3, 0), 88);
        const int dy0 = min(max(y0g - 3, 0), 88) - ry0;
        const int rd0 = dy0 - (sy - ry0);
        const int cx0 = (min(max(x0g - 3 - rx0, 0), 48)) & ~3;
        const int cd0 = cx0 + q4 * 4 - (sx - rx0);
        const int qpix = yabs * WW + xabs;

        const uint2 qw = *(const uint2*)(qkv + ((size_t)(b * 16 + h) * HWSZ + qpix) * 16 + q4 * 4);
        const short8 qb = mk8(qw.x, qw.y, 0u, 0u);

        float ev[9][4];
        float vs = 0.f;
        #pragma unroll
        for (int t = 0; t < 9; ++t) {
            const int trow = min(dy0 + t, 12);
            const uint2 kk = *(const uint2*)&Ks[(trow * 64 + cx0 + m) * 16 + q4 * 4];
            f32x4 lg = __builtin_amdgcn_mfma_f32_16x16x32_bf16(
                mk8(kk.x, kk.y, kk.x, kk.y), qb, (f32x4){0.f, 0.f, 0.f, 0.f}, 0, 0, 0);
            const bool rv = (u32)(t + rd0) < 8u;
            #pragma unroll
            for (int r = 0; r < 4; ++r) {
                const bool ok = rv && ((u32)(cd0 + r) < 8u);
                const float e = ok ? __expf(lg[r] * 0.25f) : 0.f;
                ev[t][r] = e;
                vs += e;
            }
        }
        vs += __shfl_xor(vs, 16);
        vs += __shfl_xor(vs, 32);
        const float inv = 1.0f / vs;

        u32 pd0[9], pd1[9];
        #pragma unroll
        for (int t = 0; t < 9; ++t) {
            pd0[t] = (u32)f2bf(ev[t][0] * inv) | ((u32)f2bf(ev[t][1] * inv) << 16);
            pd1[t] = (u32)f2bf(ev[t][2] * inv) | ((u32)f2bf(ev[t][3] * inv) << 16);
        }

        f32x4 acc = {};
        #pragma unroll
        for (int t = 0; t < 9; ++t) {
            const int trow = min(dy0 + t, 12);
            const uint2 va = *(const uint2*)&VsT[m * 840 + trow * 64 + cx0 + q4 * 4];
            acc = __builtin_amdgcn_mfma_f32_16x16x32_bf16(
                mk8(va.x, va.y, va.x, va.y), mk8(pd0[t], pd1[t], 0u, 0u), acc, 0, 0, 0);
        }

        uint2 od;
        od.x = (u32)f2bf(acc[0]) | ((u32)f2bf(acc[1]) << 16);
        od.y = (u32)f2bf(acc[2]) | ((u32)f2bf(acc[3]) << 16);
        *(uint2*)(attn_out + ((size_t)(b * 16 + h * 2 + (q4 >> 1)) * HWSZ + qpix) * 8
                  + (q4 & 1) * 4) = od;
    }
}

// ---------------------------------------------------------------------------
extern "C" void kernel_launch(void* const* d_in, const int* in_sizes, int n_in,
                              void* d_out, int out_size, void* d_ws, size_t ws_size,
                              hipStream_t stream) {
    const float* x      = (const float*)d_in[0];
    const float* gamma  = (const float*)d_in[1];
    const float* beta   = (const float*)d_in[2];
    const float* qkv_w  = (const float*)d_in[3];
    const float* qkv_b  = (const float*)d_in[4];
    const float* proj_w = (const float*)d_in[5];
    const float* proj_b = (const float*)d_in[6];
    float* out = (float*)d_out;

    char* wsb = (char*)d_ws;
    float* partial = (float*)wsb;                                   // 512 f32
    u16* Wq    = (u16*)(wsb + 4096);                                // 49,152 u16
    u16* Wp    = Wq + 16 * 384 * 8;                                 // 16,384 u16
    u16* qkvp  = Wp + 16 * 128 * 8;                                 // 4,718,592 u16 (q,k planes)
    u16* vT    = qkvp + (size_t)BATCH * 16 * HWSZ * HD;             // 2,359,296 u16 (V ch-major)
    u16* attnp = vT + (size_t)BATCH * 8 * HD * HWSZ;                // 2,359,296 u16

    gn_wpack<<<288, 256, 0, stream>>>(x, partial, qkv_w, proj_w, Wq, Wp);

    qkv_fused<<<432, 256, 0, stream>>>(x, partial, gamma, beta, Wq, qkv_b, qkvp, vT);

    natten_mfma<<<dim3(32, HEADS, BATCH), 384, 0, stream>>>(qkvp, vT, attnp);

    proj_gemm<<<288, 256, 0, stream>>>(Wp, attnp, proj_b, out);
}

// Round 9
// 41.683 us; speedup vs baseline: 3.4419x; 1.0353x over previous
//
#include <hip/hip_runtime.h>
#include <hip/hip_bf16.h>

typedef unsigned short u16;
typedef unsigned int   u32;
typedef __attribute__((ext_vector_type(8))) short short8;
typedef __attribute__((ext_vector_type(4))) float f32x4;

#define BATCH 2
#define CCH   128
#define HH    96
#define WW    96
#define HWSZ  9216
#define HEADS 8
#define HD    16
#define GROUPS 32
#define EPSV  1e-6f

// fp32 -> bf16 RNE via hardware convert (fptrunc lowers to v_cvt_pk_bf16_f32)
static __device__ __forceinline__ u16 f2bf(float f) {
    return __builtin_bit_cast(u16, (__bf16)f);
}
static __device__ __forceinline__ u32 pk2(float a, float b) {
    return (u32)f2bf(a) | ((u32)f2bf(b) << 16);
}
static __device__ __forceinline__ short8 mk8(u32 a, u32 b, u32 c, u32 d) {
    union { short8 v; u32 w[4]; } u; u.w[0]=a; u.w[1]=b; u.w[2]=c; u.w[3]=d; return u.v;
}

// ---------------------------------------------------------------------------
// Fused: GN partial stats (blocks 0..255) + weight packing (blocks 256..287).
// ---------------------------------------------------------------------------
__global__ __launch_bounds__(256) void gn_wpack(const float* __restrict__ x,
                                                float* __restrict__ partial,
                                                const float* __restrict__ qkv_w,
                                                const float* __restrict__ proj_w,
                                                u16* __restrict__ Wq, u16* __restrict__ Wp) {
    if (blockIdx.x < 256) {
        const int bq = blockIdx.x;
        const float4* base = (const float4*)(x + (size_t)bq * 9216);
        float s = 0.f, ss = 0.f;
        #pragma unroll
        for (int i = 0; i < 9; ++i) {
            float4 v = base[threadIdx.x + i * 256];
            s  += v.x + v.y + v.z + v.w;
            ss += v.x * v.x + v.y * v.y + v.z * v.z + v.w * v.w;
        }
        #pragma unroll
        for (int off = 32; off > 0; off >>= 1) {
            s  += __shfl_down(s, off);
            ss += __shfl_down(ss, off);
        }
        __shared__ float rs[4], rss[4];
        const int wid = threadIdx.x >> 6, lane = threadIdx.x & 63;
        if (lane == 0) { rs[wid] = s; rss[wid] = ss; }
        __syncthreads();
        if (threadIdx.x == 0) {
            partial[2 * bq]     = rs[0] + rs[1] + rs[2] + rs[3];
            partial[2 * bq + 1] = rss[0] + rss[1] + rss[2] + rss[3];
        }
    } else {
        const int t = (blockIdx.x - 256) * 256 + threadIdx.x;
        if (t < 16 * 384) {
            int cb = t / 384, o = t % 384;
            u16 pk[8];
            #pragma unroll
            for (int j = 0; j < 8; ++j) pk[j] = f2bf(qkv_w[o * 128 + cb * 8 + j]);
            uint4 r;
            r.x = (u32)pk[0] | ((u32)pk[1] << 16); r.y = (u32)pk[2] | ((u32)pk[3] << 16);
            r.z = (u32)pk[4] | ((u32)pk[5] << 16); r.w = (u32)pk[6] | ((u32)pk[7] << 16);
            *(uint4*)(Wq + (size_t)t * 8) = r;
        } else if (t < 16 * 384 + 16 * 128) {
            int i = t - 16 * 384;
            int cb = i / 128, o = i % 128;
            u16 pk[8];
            #pragma unroll
            for (int j = 0; j < 8; ++j) pk[j] = f2bf(proj_w[o * 128 + cb * 8 + j]);
            uint4 r;
            r.x = (u32)pk[0] | ((u32)pk[1] << 16); r.y = (u32)pk[2] | ((u32)pk[3] << 16);
            r.z = (u32)pk[4] | ((u32)pk[5] << 16); r.w = (u32)pk[6] | ((u32)pk[7] << 16);
            *(uint4*)(Wp + (size_t)i * 8) = r;
        }
    }
}

// ---------------------------------------------------------------------------
// QKV GEMM fused with GroupNorm-normalize staging. 432 blocks, XCD-chunk
// swizzled. Uniform epilogue: all 24 planes pixel-major qkvp[b*24+pl][p][16].
// ---------------------------------------------------------------------------
__global__ __launch_bounds__(256) void qkv_fused(const float* __restrict__ x,
                                                 const float* __restrict__ partial,
                                                 const float* __restrict__ gamma,
                                                 const float* __restrict__ beta,
                                                 const u16* __restrict__ Wq,
                                                 const float* __restrict__ qkv_b,
                                                 u16* __restrict__ qkvp) {
    __shared__ float scale[CCH], shift[CCH];
    __shared__ u16 Xt[16 * 128 * 8];   // 32 KB
    const int t = threadIdx.x;
    const int pph = blockIdx.x;                  // 0..431
    const int L = (pph & 7) * 54 + (pph >> 3);   // chunk swizzle (432 = 8*54)
    const int b = L / 216;
    const int r = L % 216;
    const int pt = r / 3, ot = r % 3;

    if (t < CCH) {
        const int c = t, g = c >> 2, bg = b * GROUPS + g;
        float S = 0.f, SS = 0.f;
        #pragma unroll
        for (int q = 0; q < 4; ++q) {
            S  += partial[2 * (bg * 4 + q)];
            SS += partial[2 * (bg * 4 + q) + 1];
        }
        const float mean = S * (1.f / 36864.f);
        const float rstd = rsqrtf(SS * (1.f / 36864.f) - mean * mean + EPSV);
        const float sc = rstd * gamma[c];
        scale[c] = sc;
        shift[c] = beta[c] - mean * sc;
    }
    __syncthreads();

    {
        const int px = t & 127, chh = t >> 7;
        const float* xb = x + (size_t)b * CCH * HWSZ + (size_t)pt * 128 + px;
        #pragma unroll
        for (int cbi = 0; cbi < 8; ++cbi) {
            const int cb = chh * 8 + cbi;
            u16 pk[8];
            #pragma unroll
            for (int j = 0; j < 8; ++j) {
                const int c = cb * 8 + j;
                pk[j] = f2bf(__builtin_fmaf(xb[(size_t)c * HWSZ], scale[c], shift[c]));
            }
            uint4 o;
            o.x = (u32)pk[0] | ((u32)pk[1] << 16);
            o.y = (u32)pk[2] | ((u32)pk[3] << 16);
            o.z = (u32)pk[4] | ((u32)pk[5] << 16);
            o.w = (u32)pk[6] | ((u32)pk[7] << 16);
            *(uint4*)&Xt[((size_t)cb * 128 + px) * 8] = o;
        }
    }
    __syncthreads();

    const int l = t & 63, w = t >> 6;
    const int OB = ot * 128 + (w & 1) * 64;
    const int PL = (w >> 1) * 64;
    const int q = l >> 4, lo = l & 15;

    float bv[4][4];
    #pragma unroll
    for (int of = 0; of < 4; ++of)
        #pragma unroll
        for (int r2 = 0; r2 < 4; ++r2) bv[of][r2] = qkv_b[OB + of * 16 + q * 4 + r2];

    f32x4 acc[4][4] = {};
    #pragma unroll
    for (int ks = 0; ks < 4; ++ks) {
        const int cb = ks * 4 + q;
        short8 a[4];
        #pragma unroll
        for (int of = 0; of < 4; ++of)
            a[of] = *(const short8*)(Wq + ((size_t)cb * 384 + OB + of * 16 + lo) * 8);
        #pragma unroll
        for (int pf = 0; pf < 4; ++pf) {
            short8 bb = *(const short8*)&Xt[((size_t)cb * 128 + PL + pf * 16 + lo) * 8];
            #pragma unroll
            for (int of = 0; of < 4; ++of)
                acc[of][pf] = __builtin_amdgcn_mfma_f32_16x16x32_bf16(a[of], bb, acc[of][pf], 0, 0, 0);
        }
    }

    #pragma unroll
    for (int of = 0; of < 4; ++of) {
        const int plane = b * 24 + (OB >> 4) + of;
        #pragma unroll
        for (int pf = 0; pf < 4; ++pf) {
            const int p = pt * 128 + PL + pf * 16 + lo;
            uint2 pkt;
            pkt.x = pk2(acc[of][pf][0] + bv[of][0], acc[of][pf][1] + bv[of][1]);
            pkt.y = pk2(acc[of][pf][2] + bv[of][2], acc[of][pf][3] + bv[of][3]);
            *(uint2*)(qkvp + ((size_t)plane * HWSZ + p) * 16 + q * 4) = pkt;
        }
    }
}

// ---------------------------------------------------------------------------
// Proj GEMM: 288 blocks (round-8 proven).
// ---------------------------------------------------------------------------
__global__ __launch_bounds__(256) void proj_gemm(const u16* __restrict__ Wpk,
                                                 const u16* __restrict__ Xpk,
                                                 const float* __restrict__ bias,
                                                 float* __restrict__ out_f32) {
    const int bid = blockIdx.x;              // 0..287
    const int b = bid / 144, pt = bid % 144;
    const int l = threadIdx.x & 63, w = threadIdx.x >> 6;
    const int OB = (w & 1) * 64;
    const int PB = pt * 64 + (w >> 1) * 32;
    const int q = l >> 4, lo = l & 15;
    const u16* Xb = Xpk + (size_t)b * 16 * HWSZ * 8;

    float bv[4][4];
    #pragma unroll
    for (int of = 0; of < 4; ++of)
        #pragma unroll
        for (int r = 0; r < 4; ++r) bv[of][r] = bias[OB + of * 16 + q * 4 + r];

    f32x4 acc[4][2] = {};
    #pragma unroll
    for (int ks = 0; ks < 4; ++ks) {
        const int cb = ks * 4 + q;
        short8 a[4];
        #pragma unroll
        for (int of = 0; of < 4; ++of)
            a[of] = *(const short8*)(Wpk + ((size_t)cb * 128 + OB + of * 16 + lo) * 8);
        #pragma unroll
        for (int pf = 0; pf < 2; ++pf) {
            short8 bb = *(const short8*)(Xb + ((size_t)cb * HWSZ + PB + pf * 16 + lo) * 8);
            #pragma unroll
            for (int of = 0; of < 4; ++of)
                acc[of][pf] = __builtin_amdgcn_mfma_f32_16x16x32_bf16(a[of], bb, acc[of][pf], 0, 0, 0);
        }
    }

    #pragma unroll
    for (int of = 0; of < 4; ++of) {
        #pragma unroll
        for (int pf = 0; pf < 2; ++pf) {
            const int p = PB + pf * 16 + lo;
            #pragma unroll
            for (int r = 0; r < 4; ++r) {
                const int o = OB + of * 16 + q * 4 + r;
                out_f32[((size_t)(b * 128 + o)) * HWSZ + p] = acc[of][pf][r] + bv[of][r];
            }
        }
    }
}

// ---------------------------------------------------------------------------
// MFMA NATTEN v4. K staged pixel-major; V transposed to channel-major during
// staging (scalar ds_write_b16 scatter). Softmax: additive -1e30 bias masking
// + single fused fma+exp per logit; P stored unnormalized bf16, 1/sum applied
// to the PV accumulator.
// ---------------------------------------------------------------------------
__global__ __launch_bounds__(384) void natten_mfma(const u16* __restrict__ qkv,
                                                   u16* __restrict__ attn_out) {
    __shared__ u16 Ks[13 * 64 * 16];   // 26 KB
    __shared__ u16 VsT[16 * 840];      // 26.3 KB
    const int tid = threadIdx.x;
    const int xh = blockIdx.x & 1, yb = blockIdx.x >> 1;
    const int h = blockIdx.y, b = blockIdx.z;
    const int ry0 = min(max(yb * 6 - 3, 0), 83);
    const int rx0 = xh * 32;

    for (int i = tid; i < 3328; i += 384) {
        if (i < 1664) {
            const int px = i >> 1, half = i & 1;
            const int row = px >> 6, col = px & 63;
            const u16* gp = qkv + ((size_t)(b * 24 + 8 + h) * HWSZ
                                 + (ry0 + row) * WW + rx0 + col) * 16 + half * 8;
            *(uint4*)&Ks[px * 16 + half * 8] = *(const uint4*)gp;
        } else {
            const int j2 = i - 1664;
            const int px = j2 >> 1, half = j2 & 1;
            const int row = px >> 6, col = px & 63;
            const u16* gp = qkv + ((size_t)(b * 24 + 16 + h) * HWSZ
                                 + (ry0 + row) * WW + rx0 + col) * 16 + half * 8;
            const uint4 vv = *(const uint4*)gp;
            const int ch0 = half * 8;
            VsT[(ch0 + 0) * 840 + px] = (u16)(vv.x);
            VsT[(ch0 + 1) * 840 + px] = (u16)(vv.x >> 16);
            VsT[(ch0 + 2) * 840 + px] = (u16)(vv.y);
            VsT[(ch0 + 3) * 840 + px] = (u16)(vv.y >> 16);
            VsT[(ch0 + 4) * 840 + px] = (u16)(vv.z);
            VsT[(ch0 + 5) * 840 + px] = (u16)(vv.z >> 16);
            VsT[(ch0 + 6) * 840 + px] = (u16)(vv.w);
            VsT[(ch0 + 7) * 840 + px] = (u16)(vv.w >> 16);
        }
    }
    __syncthreads();

    const int l = tid & 63, wv = tid >> 6;
    const int m = l & 15, q4 = l >> 4;
    const int yq = m >> 3, xq = m & 7;

    for (int j = 0; j < 3; ++j) {
        const int g = wv * 3 + j;
        const int gy = g / 6, gx = g % 6;
        const int y0g = yb * 6 + gy * 2, x0g = xh * 48 + gx * 8;
        const int yabs = y0g + yq, xabs = x0g + xq;
        const int sy = min(max(yabs - 3, 0), 88);
        const int sx = min(max(xabs - 3, 0), 88);
        const int dy0 = min(max(y0g - 3, 0), 88) - ry0;
        const int rd0 = dy0 - (sy - ry0);
        const int cx0 = (min(max(x0g - 3 - rx0, 0), 48)) & ~3;
        const int cd0 = cx0 + q4 * 4 - (sx - rx0);
        const int qpix = yabs * WW + xabs;

        const uint2 qw = *(const uint2*)(qkv + ((size_t)(b * 24 + h) * HWSZ + qpix) * 16 + q4 * 4);
        const short8 qb = mk8(qw.x, qw.y, 0u, 0u);

        const float NEGB = -1e30f;
        float colb[4];
        #pragma unroll
        for (int r = 0; r < 4; ++r) colb[r] = ((u32)(cd0 + r) < 8u) ? 0.f : NEGB;

        float ev[9][4];
        float vs = 0.f;
        #pragma unroll
        for (int t = 0; t < 9; ++t) {
            const int trow = min(dy0 + t, 12);
            const uint2 kk = *(const uint2*)&Ks[(trow * 64 + cx0 + m) * 16 + q4 * 4];
            f32x4 lg = __builtin_amdgcn_mfma_f32_16x16x32_bf16(
                mk8(kk.x, kk.y, kk.x, kk.y), qb, (f32x4){0.f, 0.f, 0.f, 0.f}, 0, 0, 0);
            const float rb = ((u32)(t + rd0) < 8u) ? 0.f : NEGB;
            #pragma unroll
            for (int r = 0; r < 4; ++r) {
                const float e = __expf(__builtin_fmaf(lg[r], 0.25f, colb[r] + rb));
                ev[t][r] = e;
                vs += e;
            }
        }
        vs += __shfl_xor(vs, 16);
        vs += __shfl_xor(vs, 32);
        const float inv = 1.0f / vs;

        u32 pd0[9], pd1[9];
        #pragma unroll
        for (int t = 0; t < 9; ++t) {
            pd0[t] = pk2(ev[t][0], ev[t][1]);
            pd1[t] = pk2(ev[t][2], ev[t][3]);
        }

        f32x4 acc = {};
        #pragma unroll
        for (int t = 0; t < 9; ++t) {
            const int trow = min(dy0 + t, 12);
            const uint2 va = *(const uint2*)&VsT[m * 840 + trow * 64 + cx0 + q4 * 4];
            acc = __builtin_amdgcn_mfma_f32_16x16x32_bf16(
                mk8(va.x, va.y, va.x, va.y), mk8(pd0[t], pd1[t], 0u, 0u), acc, 0, 0, 0);
        }

        uint2 od;
        od.x = pk2(acc[0] * inv, acc[1] * inv);
        od.y = pk2(acc[2] * inv, acc[3] * inv);
        *(uint2*)(attn_out + ((size_t)(b * 16 + h * 2 + (q4 >> 1)) * HWSZ + qpix) * 8
                  + (q4 & 1) * 4) = od;
    }
}

// ---------------------------------------------------------------------------
extern "C" void kernel_launch(void* const* d_in, const int* in_sizes, int n_in,
                              void* d_out, int out_size, void* d_ws, size_t ws_size,
                              hipStream_t stream) {
    const float* x      = (const float*)d_in[0];
    const float* gamma  = (const float*)d_in[1];
    const float* beta   = (const float*)d_in[2];
    const float* qkv_w  = (const float*)d_in[3];
    const float* qkv_b  = (const float*)d_in[4];
    const float* proj_w = (const float*)d_in[5];
    const float* proj_b = (const float*)d_in[6];
    float* out = (float*)d_out;

    char* wsb = (char*)d_ws;
    float* partial = (float*)wsb;                                   // 512 f32
    u16* Wq    = (u16*)(wsb + 4096);                                // 49,152 u16
    u16* Wp    = Wq + 16 * 384 * 8;                                 // 16,384 u16
    u16* qkvp  = Wp + 16 * 128 * 8;                                 // 7,077,888 u16 (24 planes)
    u16* attnp = qkvp + (size_t)BATCH * 24 * HWSZ * HD;             // 2,359,296 u16

    gn_wpack<<<288, 256, 0, stream>>>(x, partial, qkv_w, proj_w, Wq, Wp);

    qkv_fused<<<432, 256, 0, stream>>>(x, partial, gamma, beta, Wq, qkv_b, qkvp);

    natten_mfma<<<dim3(32, HEADS, BATCH), 384, 0, stream>>>(qkvp, attnp);

    proj_gemm<<<288, 256, 0, stream>>>(Wp, attnp, proj_b, out);
}